// Round 1
// baseline (1910.494 us; speedup 1.0000x reference)
//
#include <hip/hip_runtime.h>
#include <math.h>

// Problem constants: B=2, C=128, H=W=64, N=H*W=4096
// Workspace layout (floats), P = 2*4096*128 = 1,048,576 per buffer:
//   xr(0) xi(1) yr(2) yi(3) Qr(4) Qi(5) Kr(6) Ki(7) Vr(8) Vi(9)
//   attention output Or/Oi reuse xr/xi (x spectra dead after proj).

#define PI2 6.283185307179586f

// ---------------------------------------------------------------------------
// Kernel 1: forward DFT2 of x and y via two 64-point DFT stages per (b,c) plane
// grid 512 (first 256 = x planes, rest = y), block 256
// output layout: [b][n=h*64+w][c] (c contiguous), split re/im
// ---------------------------------------------------------------------------
__global__ __launch_bounds__(256) void dft2_fwd_kernel(
    const float* __restrict__ x, const float* __restrict__ y,
    float* __restrict__ xr, float* __restrict__ xi,
    float* __restrict__ yr, float* __restrict__ yi)
{
  __shared__ float Xs[4096];
  __shared__ float Tr[4096], Ti[4096];
  __shared__ float twc[64], tws[64];
  int blk = blockIdx.x;
  const float* src; float *outr, *outi;
  int plane;
  if (blk < 256) { src = x; outr = xr; outi = xi; plane = blk; }
  else           { src = y; outr = yr; outi = yi; plane = blk - 256; }
  int b = plane >> 7, c = plane & 127;
  int t = threadIdx.x;
  if (t < 64) {
    float ang = -PI2 * (float)t / 64.0f;   // e^{-2*pi*i*k/64}
    twc[t] = cosf(ang); tws[t] = sinf(ang);
  }
  const float* p = src + ((size_t)plane << 12);
  for (int i = t; i < 4096; i += 256) Xs[i] = p[i];
  __syncthreads();
  // stage 1 (over w): T[h][w'] = sum_w Xs[h][w] * e^{-i 2pi w w'/64}
  for (int j = 0; j < 16; j++) {
    int o = t + 256 * j; int h = o >> 6, wp = o & 63;
    float ar = 0.f, ai = 0.f;
    for (int w = 0; w < 64; w++) {
      int k = (w * wp) & 63;
      float v = Xs[h * 64 + w];
      ar = fmaf(v, twc[k], ar);
      ai = fmaf(v, tws[k], ai);
    }
    Tr[h * 64 + wp] = ar; Ti[h * 64 + wp] = ai;
  }
  __syncthreads();
  // stage 2 (over h): XF[h'][w'] = sum_h T[h][w'] * e^{-i 2pi h h'/64}
  size_t ob = ((size_t)b * 4096) * 128 + c;
  for (int j = 0; j < 16; j++) {
    int o = t + 256 * j; int hp = o >> 6, wp = o & 63;
    float ar = 0.f, ai = 0.f;
    for (int h = 0; h < 64; h++) {
      int k = (h * hp) & 63;
      float cr = twc[k], ci = tws[k];
      float tr = Tr[h * 64 + wp], ti = Ti[h * 64 + wp];
      ar += tr * cr - ti * ci;
      ai += tr * ci + ti * cr;
    }
    int n = (hp << 6) + wp;
    outr[ob + (size_t)n * 128] = ar;
    outi[ob + (size_t)n * 128] = ai;
  }
}

// ---------------------------------------------------------------------------
// Kernel 2: complex linear projections. grid (64 n-tiles, 3 linears, 2 batch)
// out[n,d] = sum_c a[n,c]*W[d,c] (complex), bias_r = br-bi, bias_i = br+bi
// ---------------------------------------------------------------------------
__global__ __launch_bounds__(256) void proj_kernel(
    const float* __restrict__ xr, const float* __restrict__ xi,
    const float* __restrict__ yr, const float* __restrict__ yi,
    const float* __restrict__ Wqr, const float* __restrict__ bqr,
    const float* __restrict__ Wqi, const float* __restrict__ bqi,
    const float* __restrict__ Wkr, const float* __restrict__ bkr,
    const float* __restrict__ Wki, const float* __restrict__ bki,
    const float* __restrict__ Wvr, const float* __restrict__ bvr,
    const float* __restrict__ Wvi, const float* __restrict__ bvi,
    float* __restrict__ Qr, float* __restrict__ Qi,
    float* __restrict__ Kr, float* __restrict__ Ki,
    float* __restrict__ Vr, float* __restrict__ Vi)
{
  __shared__ float Asr[64 * 33], Asi[64 * 33], Wsr[128 * 33], Wsi[128 * 33];
  int nt = blockIdx.x, lin = blockIdx.y, b = blockIdx.z;
  const float *ar, *ai, *Wr, *Wi, *br, *bi;
  float *outr, *outi;
  if (lin == 0)      { ar = xr; ai = xi; Wr = Wqr; Wi = Wqi; br = bqr; bi = bqi; outr = Qr; outi = Qi; }
  else if (lin == 1) { ar = yr; ai = yi; Wr = Wkr; Wi = Wki; br = bkr; bi = bki; outr = Kr; outi = Ki; }
  else               { ar = yr; ai = yi; Wr = Wvr; Wi = Wvi; br = bvr; bi = bvi; outr = Vr; outi = Vi; }
  int t = threadIdx.x; int td = t & 15, tn = t >> 4;
  int n0 = nt * 64;
  size_t abase = (size_t)b * 4096 * 128 + (size_t)n0 * 128;
  float accr[4][8] = {}, acci[4][8] = {};
  for (int kk = 0; kk < 4; kk++) {
    __syncthreads();
    for (int idx = t; idx < 64 * 32; idx += 256) {
      int r = idx >> 5, ccol = idx & 31;
      Asr[r * 33 + ccol] = ar[abase + (size_t)r * 128 + kk * 32 + ccol];
      Asi[r * 33 + ccol] = ai[abase + (size_t)r * 128 + kk * 32 + ccol];
    }
    for (int idx = t; idx < 128 * 32; idx += 256) {
      int r = idx >> 5, ccol = idx & 31;
      Wsr[r * 33 + ccol] = Wr[(size_t)r * 128 + kk * 32 + ccol];
      Wsi[r * 33 + ccol] = Wi[(size_t)r * 128 + kk * 32 + ccol];
    }
    __syncthreads();
    for (int k = 0; k < 32; k++) {
      float a_r[4], a_i[4], w_r[8], w_i[8];
      #pragma unroll
      for (int i = 0; i < 4; i++) {
        a_r[i] = Asr[(tn * 4 + i) * 33 + k];
        a_i[i] = Asi[(tn * 4 + i) * 33 + k];
      }
      #pragma unroll
      for (int jj = 0; jj < 8; jj++) {
        w_r[jj] = Wsr[(td + 16 * jj) * 33 + k];
        w_i[jj] = Wsi[(td + 16 * jj) * 33 + k];
      }
      #pragma unroll
      for (int i = 0; i < 4; i++)
        #pragma unroll
        for (int jj = 0; jj < 8; jj++) {
          accr[i][jj] += a_r[i] * w_r[jj] - a_i[i] * w_i[jj];
          acci[i][jj] += a_i[i] * w_r[jj] + a_r[i] * w_i[jj];
        }
    }
  }
  for (int jj = 0; jj < 8; jj++) {
    int d = td + 16 * jj;
    float brd = br[d], bid = bi[d];
    #pragma unroll
    for (int i = 0; i < 4; i++) {
      int n = n0 + tn * 4 + i;
      size_t o = (size_t)b * 4096 * 128 + (size_t)n * 128 + d;
      outr[o] = accr[i][jj] + (brd - bid);
      outi[o] = acci[i][jj] + (brd + bid);
    }
  }
}

// ---------------------------------------------------------------------------
// Kernel 3: flash-style complex-score attention.
// grid (128 q-tiles of 32, 2 batches), block 256 = 8 tq-groups x 32 tm lanes.
// Per thread: 4 q rows x 2 m cols scores; O accum 4q x 8cc (cc in [0,256)).
// ---------------------------------------------------------------------------
__global__ __launch_bounds__(256) void attn_kernel(
    const float* __restrict__ Qr, const float* __restrict__ Qi,
    const float* __restrict__ Kr, const float* __restrict__ Ki,
    const float* __restrict__ Vr, const float* __restrict__ Vi,
    float* __restrict__ Or_, float* __restrict__ Oi_)
{
  __shared__ float Qs[2 * 32 * 128];   // r then i, stride 128 (2-way max -> free)
  __shared__ float KV[16640];          // Ktr[128*65] + Kti[128*65]; union Vs[64*256]
  __shared__ float Ps[32 * 65];
  int b = blockIdx.y, qt = blockIdx.x;
  int q0 = qt * 32;
  int t = threadIdx.x; int tm = t & 31, tq = t >> 5;
  size_t base = (size_t)b * 4096 * 128;
  for (int idx = t; idx < 32 * 128; idx += 256) {
    Qs[idx]            = Qr[base + (size_t)q0 * 128 + idx];
    Qs[32 * 128 + idx] = Qi[base + (size_t)q0 * 128 + idx];
  }
  float M[4], L[4], O[4][8];
  #pragma unroll
  for (int i = 0; i < 4; i++) {
    M[i] = -1e30f; L[i] = 0.f;
    #pragma unroll
    for (int jj = 0; jj < 8; jj++) O[i][jj] = 0.f;
  }
  float* Ktr = KV;
  float* Kti = KV + 8320;
  float* Vs  = KV;
  for (int mt = 0; mt < 64; mt++) {
    int m0 = mt * 64;
    __syncthreads();   // prior tile's PV / Ps reads done; safe to overwrite KV
    for (int idx = t; idx < 64 * 128; idx += 256) {
      int r = idx >> 7, k = idx & 127;
      Ktr[k * 65 + r] = Kr[base + (size_t)m0 * 128 + idx];
      Kti[k * 65 + r] = Ki[base + (size_t)m0 * 128 + idx];
    }
    __syncthreads();
    float sr[4][2] = {}, si[4][2] = {};
    #pragma unroll 4
    for (int k = 0; k < 128; k++) {
      float kr0 = Ktr[k * 65 + tm],      ki0 = Kti[k * 65 + tm];
      float kr1 = Ktr[k * 65 + tm + 32], ki1 = Kti[k * 65 + tm + 32];
      #pragma unroll
      for (int i = 0; i < 4; i++) {
        float qr = Qs[(tq * 4 + i) * 128 + k];
        float qi = Qs[32 * 128 + (tq * 4 + i) * 128 + k];
        sr[i][0] += qr * kr0 - qi * ki0;
        si[i][0] += qr * ki0 + qi * kr0;
        sr[i][1] += qr * kr1 - qi * ki1;
        si[i][1] += qr * ki1 + qi * kr1;
      }
    }
    // online softmax update (row groups = 32 tm lanes within half-wave)
    #pragma unroll
    for (int i = 0; i < 4; i++) {
      float s0 = sqrtf(sr[i][0] * sr[i][0] + si[i][0] * si[i][0] + 1e-8f);
      float s1 = sqrtf(sr[i][1] * sr[i][1] + si[i][1] * si[i][1] + 1e-8f);
      float mx = fmaxf(s0, s1);
      #pragma unroll
      for (int d = 16; d >= 1; d >>= 1) mx = fmaxf(mx, __shfl_xor(mx, d));
      float nm = fmaxf(M[i], mx);
      float sc = __expf(M[i] - nm);
      float p0 = __expf(s0 - nm), p1 = __expf(s1 - nm);
      float ps = p0 + p1;
      #pragma unroll
      for (int d = 16; d >= 1; d >>= 1) ps += __shfl_xor(ps, d);
      L[i] = L[i] * sc + ps;
      M[i] = nm;
      #pragma unroll
      for (int jj = 0; jj < 8; jj++) O[i][jj] *= sc;
      Ps[(tq * 4 + i) * 65 + tm]      = p0;
      Ps[(tq * 4 + i) * 65 + tm + 32] = p1;
    }
    __syncthreads();   // all done reading Kt; safe to overwrite with V
    for (int idx = t; idx < 64 * 256; idx += 256) {
      int r = idx >> 8, cc = idx & 255;
      Vs[idx] = (cc < 128) ? Vr[base + (size_t)(m0 + r) * 128 + cc]
                           : Vi[base + (size_t)(m0 + r) * 128 + cc - 128];
    }
    __syncthreads();
    for (int m = 0; m < 64; m++) {
      float p0 = Ps[(tq * 4 + 0) * 65 + m];
      float p1 = Ps[(tq * 4 + 1) * 65 + m];
      float p2 = Ps[(tq * 4 + 2) * 65 + m];
      float p3 = Ps[(tq * 4 + 3) * 65 + m];
      #pragma unroll
      for (int jj = 0; jj < 8; jj++) {
        float v = Vs[m * 256 + tm + 32 * jj];
        O[0][jj] += p0 * v;
        O[1][jj] += p1 * v;
        O[2][jj] += p2 * v;
        O[3][jj] += p3 * v;
      }
    }
  }
  #pragma unroll
  for (int i = 0; i < 4; i++) {
    float inv = 1.0f / L[i];
    int q = q0 + tq * 4 + i;
    #pragma unroll
    for (int jj = 0; jj < 8; jj++) {
      int cc = tm + 32 * jj;
      float v = O[i][jj] * inv;
      if (cc < 128) Or_[base + (size_t)q * 128 + cc] = v;
      else          Oi_[base + (size_t)q * 128 + cc - 128] = v;
    }
  }
}

// ---------------------------------------------------------------------------
// Kernel 4: inverse DFT2 (take real part), output [b][c][h][w]
// ---------------------------------------------------------------------------
__global__ __launch_bounds__(256) void idft2_kernel(
    const float* __restrict__ Or_, const float* __restrict__ Oi_,
    float* __restrict__ out)
{
  __shared__ float Ar[4096], Ai[4096], Tr[4096], Ti[4096];
  __shared__ float twc[64], tws[64];
  int plane = blockIdx.x; int b = plane >> 7, c = plane & 127;
  int t = threadIdx.x;
  if (t < 64) {
    float ang = PI2 * (float)t / 64.0f;   // e^{+2*pi*i*k/64}
    twc[t] = cosf(ang); tws[t] = sinf(ang);
  }
  size_t ibase = (size_t)b * 4096 * 128 + c;
  for (int i = t; i < 4096; i += 256) {
    Ar[i] = Or_[ibase + (size_t)i * 128];
    Ai[i] = Oi_[ibase + (size_t)i * 128];
  }
  __syncthreads();
  // stage 1 (over w'): T[h'][w] = sum_{w'} A[h'][w'] e^{+i 2pi w w'/64}
  for (int j = 0; j < 16; j++) {
    int o = t + 256 * j; int hp = o >> 6, w = o & 63;
    float tr = 0.f, ti = 0.f;
    for (int wp = 0; wp < 64; wp++) {
      int k = (wp * w) & 63;
      float cr = twc[k], ci = tws[k];
      float ar = Ar[hp * 64 + wp], ai = Ai[hp * 64 + wp];
      tr += ar * cr - ai * ci;
      ti += ai * cr + ar * ci;
    }
    Tr[hp * 64 + w] = tr; Ti[hp * 64 + w] = ti;
  }
  __syncthreads();
  // stage 2 (over h'): out[h][w] = (1/4096) Re sum_{h'} T[h'][w] e^{+i 2pi h h'/64}
  size_t obase = ((size_t)plane) << 12;
  for (int j = 0; j < 16; j++) {
    int o = t + 256 * j; int h = o >> 6, w = o & 63;
    float acc = 0.f;
    for (int hp = 0; hp < 64; hp++) {
      int k = (hp * h) & 63;
      acc += Tr[hp * 64 + w] * twc[k] - Ti[hp * 64 + w] * tws[k];
    }
    out[obase + o] = acc * (1.0f / 4096.0f);
  }
}

extern "C" void kernel_launch(void* const* d_in, const int* in_sizes, int n_in,
                              void* d_out, int out_size, void* d_ws, size_t ws_size,
                              hipStream_t stream) {
  const float* x   = (const float*)d_in[0];
  const float* y   = (const float*)d_in[1];
  const float* Wqr = (const float*)d_in[2];  const float* bqr = (const float*)d_in[3];
  const float* Wqi = (const float*)d_in[4];  const float* bqi = (const float*)d_in[5];
  const float* Wkr = (const float*)d_in[6];  const float* bkr = (const float*)d_in[7];
  const float* Wki = (const float*)d_in[8];  const float* bki = (const float*)d_in[9];
  const float* Wvr = (const float*)d_in[10]; const float* bvr = (const float*)d_in[11];
  const float* Wvi = (const float*)d_in[12]; const float* bvi = (const float*)d_in[13];
  float* ws = (float*)d_ws;
  const size_t P = (size_t)2 * 4096 * 128;
  if (ws_size < 10 * P * sizeof(float)) return;  // workspace too small: fail loudly (zero output)
  float* xr = ws + 0 * P; float* xi = ws + 1 * P;
  float* yr = ws + 2 * P; float* yi = ws + 3 * P;
  float* Qr = ws + 4 * P; float* Qi = ws + 5 * P;
  float* Kr = ws + 6 * P; float* Ki = ws + 7 * P;
  float* Vr = ws + 8 * P; float* Vi = ws + 9 * P;
  float* Or_ = xr; float* Oi_ = xi;   // reuse x spectra (dead after proj)
  float* out = (float*)d_out;

  hipLaunchKernelGGL(dft2_fwd_kernel, dim3(512), dim3(256), 0, stream,
                     x, y, xr, xi, yr, yi);
  hipLaunchKernelGGL(proj_kernel, dim3(64, 3, 2), dim3(256), 0, stream,
                     xr, xi, yr, yi,
                     Wqr, bqr, Wqi, bqi, Wkr, bkr, Wki, bki, Wvr, bvr, Wvi, bvi,
                     Qr, Qi, Kr, Ki, Vr, Vi);
  hipLaunchKernelGGL(attn_kernel, dim3(128, 2), dim3(256), 0, stream,
                     Qr, Qi, Kr, Ki, Vr, Vi, Or_, Oi_);
  hipLaunchKernelGGL(idft2_kernel, dim3(256), dim3(256), 0, stream,
                     Or_, Oi_, out);
}

// Round 2
// 492.629 us; speedup vs baseline: 3.8782x; 3.8782x over previous
//
#include <hip/hip_runtime.h>
#include <math.h>

// B=2, C=128, H=W=64, N=4096.
// ws layout (bytes):
//   [0,8M)   Qpk  bf16 frag-packed  [b][tq(256)][a(4)][s(4)][l(64)][j(8)]
//   [8M,16M) Kpk  bf16 frag-packed  [b][mt(64)][a(4)][tml(4)][s(4)][l(64)][j(8)]  (64KB per (b,mt))
//   [16M,20M)Vpk  bf16 frag-packed  [b][sm(128)][tc(16)][l(64)][j(8)]  (cc: 0-127=Vr,128-255=Vi)
//   [20M,36M) spectra xr,xi,yr,yi fp32 (phase1-2); Or,Oi fp32 overlay [20M,28M) (phase4-5)
// a: 0=hi(re),1=lo(re),2=hi(im),3=lo(im). frag element map: lane l holds X[row=l&15][k=32s+8*(l>>4)+j]

#define PI2 6.283185307179586f

typedef __attribute__((ext_vector_type(8))) short short8;
typedef __attribute__((ext_vector_type(4))) float f32x4;

#define MFMA16(A,B,C) __builtin_amdgcn_mfma_f32_16x16x32_bf16((A),(B),(C),0,0,0)

__device__ inline unsigned short f2bf(float x){
  union{float f; unsigned int u;} a; a.f = x;
  unsigned int r = (a.u + 0x7fffu + ((a.u>>16)&1u)) >> 16;
  return (unsigned short)r;
}
__device__ inline float bf2f(unsigned short h){
  union{unsigned int u; float f;} a; a.u = ((unsigned int)h)<<16; return a.f;
}
__device__ inline short8 neg8(short8 x){
  union{short8 v; unsigned int u[4];} a; a.v = x;
  a.u[0]^=0x80008000u; a.u[1]^=0x80008000u; a.u[2]^=0x80008000u; a.u[3]^=0x80008000u;
  return a.v;
}
__device__ inline void gload_lds16(const void* g, void* lds){
  __builtin_amdgcn_global_load_lds((const __attribute__((address_space(1))) unsigned int*)g,
                                   (__attribute__((address_space(3))) unsigned int*)lds,
                                   16, 0, 0);
}

// ---------------------------------------------------------------------------
// Kernel 1: forward DFT2 of x and y (two 64-pt DFT stages per (b,c) plane)
// ---------------------------------------------------------------------------
__global__ __launch_bounds__(256) void dft2_fwd_kernel(
    const float* __restrict__ x, const float* __restrict__ y,
    float* __restrict__ xr, float* __restrict__ xi,
    float* __restrict__ yr, float* __restrict__ yi)
{
  __shared__ float Xs[4096];
  __shared__ float Tr[4096], Ti[4096];
  __shared__ float twc[64], tws[64];
  int blk = blockIdx.x;
  const float* src; float *outr, *outi;
  int plane;
  if (blk < 256) { src = x; outr = xr; outi = xi; plane = blk; }
  else           { src = y; outr = yr; outi = yi; plane = blk - 256; }
  int b = plane >> 7, c = plane & 127;
  int t = threadIdx.x;
  if (t < 64) {
    float ang = -PI2 * (float)t / 64.0f;
    twc[t] = cosf(ang); tws[t] = sinf(ang);
  }
  const float* p = src + ((size_t)plane << 12);
  for (int i = t; i < 4096; i += 256) Xs[i] = p[i];
  __syncthreads();
  for (int j = 0; j < 16; j++) {
    int o = t + 256 * j; int h = o >> 6, wp = o & 63;
    float ar = 0.f, ai = 0.f;
    for (int w = 0; w < 64; w++) {
      int k = (w * wp) & 63;
      float v = Xs[h * 64 + w];
      ar = fmaf(v, twc[k], ar);
      ai = fmaf(v, tws[k], ai);
    }
    Tr[h * 64 + wp] = ar; Ti[h * 64 + wp] = ai;
  }
  __syncthreads();
  size_t ob = ((size_t)b * 4096) * 128 + c;
  for (int j = 0; j < 16; j++) {
    int o = t + 256 * j; int hp = o >> 6, wp = o & 63;
    float ar = 0.f, ai = 0.f;
    for (int h = 0; h < 64; h++) {
      int k = (h * hp) & 63;
      float cr = twc[k], ci = tws[k];
      float tr = Tr[h * 64 + wp], ti = Ti[h * 64 + wp];
      ar += tr * cr - ti * ci;
      ai += tr * ci + ti * cr;
    }
    int n = (hp << 6) + wp;
    outr[ob + (size_t)n * 128] = ar;
    outi[ob + (size_t)n * 128] = ai;
  }
}

// ---------------------------------------------------------------------------
// Kernel 2: complex projections, epilogue writes MFMA-frag-packed bf16 (+split)
// ---------------------------------------------------------------------------
__global__ __launch_bounds__(256) void proj_pack_kernel(
    const float* __restrict__ xr, const float* __restrict__ xi,
    const float* __restrict__ yr, const float* __restrict__ yi,
    const float* __restrict__ Wqr, const float* __restrict__ bqr,
    const float* __restrict__ Wqi, const float* __restrict__ bqi,
    const float* __restrict__ Wkr, const float* __restrict__ bkr,
    const float* __restrict__ Wki, const float* __restrict__ bki,
    const float* __restrict__ Wvr, const float* __restrict__ bvr,
    const float* __restrict__ Wvi, const float* __restrict__ bvi,
    unsigned short* __restrict__ Qpk, unsigned short* __restrict__ Kpk,
    unsigned short* __restrict__ Vpk)
{
  __shared__ float Asr[64 * 33], Asi[64 * 33], Wsr[128 * 33], Wsi[128 * 33];
  int nt = blockIdx.x, lin = blockIdx.y, b = blockIdx.z;
  const float *ar, *ai, *Wr, *Wi, *br_, *bi_;
  if (lin == 0)      { ar = xr; ai = xi; Wr = Wqr; Wi = Wqi; br_ = bqr; bi_ = bqi; }
  else if (lin == 1) { ar = yr; ai = yi; Wr = Wkr; Wi = Wki; br_ = bkr; bi_ = bki; }
  else               { ar = yr; ai = yi; Wr = Wvr; Wi = Wvi; br_ = bvr; bi_ = bvi; }
  int t = threadIdx.x; int td = t & 15, tn = t >> 4;
  int n0 = nt * 64;
  size_t abase = (size_t)b * 4096 * 128 + (size_t)n0 * 128;
  float accr[4][8] = {}, acci[4][8] = {};
  for (int kk = 0; kk < 4; kk++) {
    __syncthreads();
    for (int idx = t; idx < 64 * 32; idx += 256) {
      int r = idx >> 5, ccol = idx & 31;
      Asr[r * 33 + ccol] = ar[abase + (size_t)r * 128 + kk * 32 + ccol];
      Asi[r * 33 + ccol] = ai[abase + (size_t)r * 128 + kk * 32 + ccol];
    }
    for (int idx = t; idx < 128 * 32; idx += 256) {
      int r = idx >> 5, ccol = idx & 31;
      Wsr[r * 33 + ccol] = Wr[(size_t)r * 128 + kk * 32 + ccol];
      Wsi[r * 33 + ccol] = Wi[(size_t)r * 128 + kk * 32 + ccol];
    }
    __syncthreads();
    for (int k = 0; k < 32; k++) {
      float a_r[4], a_i[4], w_r[8], w_i[8];
      #pragma unroll
      for (int i = 0; i < 4; i++) {
        a_r[i] = Asr[(tn * 4 + i) * 33 + k];
        a_i[i] = Asi[(tn * 4 + i) * 33 + k];
      }
      #pragma unroll
      for (int jj = 0; jj < 8; jj++) {
        w_r[jj] = Wsr[(td + 16 * jj) * 33 + k];
        w_i[jj] = Wsi[(td + 16 * jj) * 33 + k];
      }
      #pragma unroll
      for (int i = 0; i < 4; i++)
        #pragma unroll
        for (int jj = 0; jj < 8; jj++) {
          accr[i][jj] += a_r[i] * w_r[jj] - a_i[i] * w_i[jj];
          acci[i][jj] += a_i[i] * w_r[jj] + a_r[i] * w_i[jj];
        }
    }
  }
  for (int jj = 0; jj < 8; jj++) {
    int d = td + 16 * jj;
    float brd = br_[d], bid = bi_[d];
    #pragma unroll
    for (int i = 0; i < 4; i++) {
      int n = n0 + tn * 4 + i;
      float cr = accr[i][jj] + (brd - bid);
      float ci = acci[i][jj] + (brd + bid);
      if (lin <= 1) {
        unsigned short rh = f2bf(cr); unsigned short rl = f2bf(cr - bf2f(rh));
        unsigned short ih = f2bf(ci); unsigned short il = f2bf(ci - bf2f(ih));
        int s = d >> 5, j = d & 7;
        int lq = ((d & 31) >> 3) * 16 + (n & 15);
        if (lin == 0) {
          int tqi = n >> 4;
          size_t base = ((size_t)((b * 256 + tqi) * 16 + s)) * 512 + (size_t)lq * 8 + j;
          Qpk[base + 0 * 2048] = rh; Qpk[base + 1 * 2048] = rl;
          Qpk[base + 2 * 2048] = ih; Qpk[base + 3 * 2048] = il;
        } else {
          int mt2 = n >> 6, tml = (n >> 4) & 3;
          size_t base = ((size_t)((b * 64 + mt2) * 64 + tml * 4 + s)) * 512 + (size_t)lq * 8 + j;
          Kpk[base + 0 * 8192] = rh; Kpk[base + 1 * 8192] = rl;
          Kpk[base + 2 * 8192] = ih; Kpk[base + 3 * 8192] = il;
        }
      } else {
        int sm = n >> 5, jv = n & 7;
        int lv = ((n & 31) >> 3) * 16 + (d & 15);
        size_t b0 = ((size_t)((b * 128 + sm) * 16 + (d >> 4))) * 512 + (size_t)lv * 8 + jv;
        size_t b1 = ((size_t)((b * 128 + sm) * 16 + ((d + 128) >> 4))) * 512 + (size_t)lv * 8 + jv;
        Vpk[b0] = f2bf(cr);
        Vpk[b1] = f2bf(ci);
      }
    }
  }
}

// ---------------------------------------------------------------------------
// Kernel 3: MFMA flash attention with split-bf16 complex scores.
// grid (128 qtiles of 32, 2 b), 256 thr = 4 waves; wave w: qg=w&1 (16 rows),
// mh=w>>1 (m-half for QK, cc-half for PV). K tile dbuf'd in LDS (64KB each).
// ---------------------------------------------------------------------------
__global__ __launch_bounds__(256, 1) void attn_mfma_kernel(
    const short* __restrict__ Qpk, const short* __restrict__ Kpk,
    const short* __restrict__ Vpk,
    float* __restrict__ Or_, float* __restrict__ Oi_)
{
  __shared__ __align__(16) short Klds[2][32768];
  __shared__ __align__(16) short Pfrag[4 * 512];
  __shared__ float rmax[2][16][2];
  __shared__ float rsum[2][16][2];

  const int b = blockIdx.y, qt = blockIdx.x;
  const int t = threadIdx.x;
  const int w = t >> 6, l = t & 63;
  const int qg = w & 1, mh = w >> 1;
  const int g = l >> 4, c = l & 15;

  // preload Q fragments (hi/lo, re/im, 4 k-steps)
  const short8* Qp8 = (const short8*)Qpk;
  const int tq = qt * 2 + qg;
  short8 Qf[4][4];
  #pragma unroll
  for (int a = 0; a < 4; a++)
    #pragma unroll
    for (int s = 0; s < 4; s++)
      Qf[a][s] = Qp8[((size_t)((b * 256 + tq) * 16 + a * 4 + s)) * 64 + l];
  short8 nQih[4], nQil[4];
  #pragma unroll
  for (int s = 0; s < 4; s++) { nQih[s] = neg8(Qf[2][s]); nQil[s] = neg8(Qf[3][s]); }

  f32x4 O[8], M, L;
  #pragma unroll
  for (int nt = 0; nt < 8; nt++) O[nt] = (f32x4){0.f, 0.f, 0.f, 0.f};
  M = (f32x4){-3e38f, -3e38f, -3e38f, -3e38f};
  L = (f32x4){0.f, 0.f, 0.f, 0.f};

  const char* Kg = (const char*)Kpk;
  {
    const char* gsrc = Kg + ((size_t)(b * 64) << 16);
    char* lb = (char*)&Klds[0][0];
    #pragma unroll
    for (int i2 = 0; i2 < 16; i2++) {
      int ch = i2 * 4 + w;
      gload_lds16(gsrc + ch * 1024 + l * 16, lb + ch * 1024);
    }
  }
  const short8* Vp8 = (const short8*)Vpk;

  for (int mt = 0; mt < 64; mt++) {
    const int cur = mt & 1;
    __syncthreads();                 // drains vmcnt -> Klds[cur] ready; recycles Pfrag/stats
    if (mt + 1 < 64) {
      const char* gsrc = Kg + ((size_t)(b * 64 + mt + 1) << 16);
      char* lb = (char*)&Klds[cur ^ 1][0];
      #pragma unroll
      for (int i2 = 0; i2 < 16; i2++) {
        int ch = i2 * 4 + w;
        gload_lds16(gsrc + ch * 1024 + l * 16, lb + ch * 1024);
      }
    }
    // ---- QK^T (split bf16: hh + hl + lh) ----
    const short8* kb8 = (const short8*)&Klds[cur][0];
    f32x4 sr[2], si[2];
    #pragma unroll
    for (int tm = 0; tm < 2; tm++) { sr[tm] = (f32x4){0,0,0,0}; si[tm] = (f32x4){0,0,0,0}; }
    #pragma unroll
    for (int s = 0; s < 4; s++) {
      #pragma unroll
      for (int tm = 0; tm < 2; tm++) {
        const int tml = 2 * mh + tm;
        short8 Brh = kb8[((0 * 4 + tml) * 4 + s) * 64 + l];
        short8 Brl = kb8[((1 * 4 + tml) * 4 + s) * 64 + l];
        short8 Bih = kb8[((2 * 4 + tml) * 4 + s) * 64 + l];
        short8 Bil = kb8[((3 * 4 + tml) * 4 + s) * 64 + l];
        sr[tm] = MFMA16(Qf[0][s], Brh, sr[tm]);
        si[tm] = MFMA16(Qf[0][s], Bih, si[tm]);
        sr[tm] = MFMA16(Qf[0][s], Brl, sr[tm]);
        si[tm] = MFMA16(Qf[0][s], Bil, si[tm]);
        sr[tm] = MFMA16(Qf[1][s], Brh, sr[tm]);
        si[tm] = MFMA16(Qf[1][s], Bih, si[tm]);
        sr[tm] = MFMA16(nQih[s], Bih, sr[tm]);
        si[tm] = MFMA16(Qf[2][s], Brh, si[tm]);
        sr[tm] = MFMA16(nQih[s], Bil, sr[tm]);
        si[tm] = MFMA16(Qf[2][s], Brl, si[tm]);
        sr[tm] = MFMA16(nQil[s], Bih, sr[tm]);
        si[tm] = MFMA16(Qf[3][s], Brh, si[tm]);
      }
    }
    // ---- scores + online softmax ----
    f32x4 s0, s1, mx;
    #pragma unroll
    for (int r = 0; r < 4; r++) {
      s0[r] = sqrtf(sr[0][r] * sr[0][r] + si[0][r] * si[0][r] + 1e-8f);
      s1[r] = sqrtf(sr[1][r] * sr[1][r] + si[1][r] * si[1][r] + 1e-8f);
      mx[r] = fmaxf(s0[r], s1[r]);
    }
    #pragma unroll
    for (int d = 1; d < 16; d <<= 1) {
      #pragma unroll
      for (int r = 0; r < 4; r++) mx[r] = fmaxf(mx[r], __shfl_xor(mx[r], d));
    }
    if (c < 4) rmax[qg][4 * g + c][mh] = mx[c];
    __syncthreads();
    f32x4 nm, esc, p0, p1, ps;
    #pragma unroll
    for (int r = 0; r < 4; r++) {
      float v = fmaxf(rmax[qg][4 * g + r][0], rmax[qg][4 * g + r][1]);
      nm[r] = fmaxf(M[r], v);
      esc[r] = __expf(M[r] - nm[r]);
      M[r] = nm[r];
      p0[r] = __expf(s0[r] - nm[r]);
      p1[r] = __expf(s1[r] - nm[r]);
      ps[r] = p0[r] + p1[r];
    }
    #pragma unroll
    for (int d = 1; d < 16; d <<= 1) {
      #pragma unroll
      for (int r = 0; r < 4; r++) ps[r] += __shfl_xor(ps[r], d);
    }
    if (c < 4) rsum[qg][4 * g + c][mh] = ps[c];
    #pragma unroll
    for (int tm = 0; tm < 2; tm++) {
      int mm = 16 * tm + c;
      int lpb = (mm >> 3) * 16;
      int j = mm & 7;
      #pragma unroll
      for (int r = 0; r < 4; r++) {
        float p = (tm == 0) ? p0[r] : p1[r];
        Pfrag[(qg * 2 + mh) * 512 + (lpb + 4 * g + r) * 8 + j] = (short)f2bf(p);
      }
    }
    __syncthreads();
    #pragma unroll
    for (int r = 0; r < 4; r++) {
      L[r] = L[r] * esc[r] + rsum[qg][4 * g + r][0] + rsum[qg][4 * g + r][1];
      #pragma unroll
      for (int nt = 0; nt < 8; nt++) O[nt][r] *= esc[r];
    }
    // ---- PV (P bf16 A-frags from LDS, V B-frags direct from global) ----
    #pragma unroll
    for (int ks = 0; ks < 2; ks++) {
      short8 Pa = *(const short8*)&Pfrag[(qg * 2 + ks) * 512 + l * 8];
      const size_t vb = ((size_t)((b * 128 + mt * 2 + ks) * 16 + mh * 8)) * 64 + l;
      #pragma unroll
      for (int nt = 0; nt < 8; nt++) {
        short8 Vb = Vp8[vb + (size_t)nt * 64];
        O[nt] = MFMA16(Pa, Vb, O[nt]);
      }
    }
  }
  // ---- normalize + write out ----
  const size_t base = (size_t)b * 4096 * 128;
  f32x4 inv;
  #pragma unroll
  for (int r = 0; r < 4; r++) inv[r] = 1.0f / L[r];
  #pragma unroll
  for (int nt = 0; nt < 8; nt++) {
    int cc = mh * 128 + nt * 16 + c;
    #pragma unroll
    for (int r = 0; r < 4; r++) {
      int row = qt * 32 + qg * 16 + 4 * g + r;
      float v = O[nt][r] * inv[r];
      if (cc < 128) Or_[base + (size_t)row * 128 + cc] = v;
      else          Oi_[base + (size_t)row * 128 + cc - 128] = v;
    }
  }
}

// ---------------------------------------------------------------------------
// Kernel 4: inverse DFT2 (real part), output [b][c][h][w]
// ---------------------------------------------------------------------------
__global__ __launch_bounds__(256) void idft2_kernel(
    const float* __restrict__ Or_, const float* __restrict__ Oi_,
    float* __restrict__ out)
{
  __shared__ float Ar[4096], Ai[4096], Tr[4096], Ti[4096];
  __shared__ float twc[64], tws[64];
  int plane = blockIdx.x; int b = plane >> 7, c = plane & 127;
  int t = threadIdx.x;
  if (t < 64) {
    float ang = PI2 * (float)t / 64.0f;
    twc[t] = cosf(ang); tws[t] = sinf(ang);
  }
  size_t ibase = (size_t)b * 4096 * 128 + c;
  for (int i = t; i < 4096; i += 256) {
    Ar[i] = Or_[ibase + (size_t)i * 128];
    Ai[i] = Oi_[ibase + (size_t)i * 128];
  }
  __syncthreads();
  for (int j = 0; j < 16; j++) {
    int o = t + 256 * j; int hp = o >> 6, w = o & 63;
    float tr = 0.f, ti = 0.f;
    for (int wp = 0; wp < 64; wp++) {
      int k = (wp * w) & 63;
      float cr = twc[k], ci = tws[k];
      float ar = Ar[hp * 64 + wp], ai = Ai[hp * 64 + wp];
      tr += ar * cr - ai * ci;
      ti += ai * cr + ar * ci;
    }
    Tr[hp * 64 + w] = tr; Ti[hp * 64 + w] = ti;
  }
  __syncthreads();
  size_t obase = ((size_t)plane) << 12;
  for (int j = 0; j < 16; j++) {
    int o = t + 256 * j; int h = o >> 6, w = o & 63;
    float acc = 0.f;
    for (int hp = 0; hp < 64; hp++) {
      int k = (hp * h) & 63;
      acc += Tr[hp * 64 + w] * twc[k] - Ti[hp * 64 + w] * tws[k];
    }
    out[obase + o] = acc * (1.0f / 4096.0f);
  }
}

extern "C" void kernel_launch(void* const* d_in, const int* in_sizes, int n_in,
                              void* d_out, int out_size, void* d_ws, size_t ws_size,
                              hipStream_t stream) {
  const float* x   = (const float*)d_in[0];
  const float* y   = (const float*)d_in[1];
  const float* Wqr = (const float*)d_in[2];  const float* bqr = (const float*)d_in[3];
  const float* Wqi = (const float*)d_in[4];  const float* bqi = (const float*)d_in[5];
  const float* Wkr = (const float*)d_in[6];  const float* bkr = (const float*)d_in[7];
  const float* Wki = (const float*)d_in[8];  const float* bki = (const float*)d_in[9];
  const float* Wvr = (const float*)d_in[10]; const float* bvr = (const float*)d_in[11];
  const float* Wvi = (const float*)d_in[12]; const float* bvi = (const float*)d_in[13];
  char* wsb = (char*)d_ws;
  if (ws_size < ((size_t)36 << 20)) return;  // need 36 MiB
  unsigned short* Qpk = (unsigned short*)(wsb);
  unsigned short* Kpk = (unsigned short*)(wsb + ((size_t)8 << 20));
  unsigned short* Vpk = (unsigned short*)(wsb + ((size_t)16 << 20));
  float* xr = (float*)(wsb + ((size_t)20 << 20));
  float* xi = (float*)(wsb + ((size_t)24 << 20));
  float* yr = (float*)(wsb + ((size_t)28 << 20));
  float* yi = (float*)(wsb + ((size_t)32 << 20));
  float* Or_ = (float*)(wsb + ((size_t)20 << 20));  // overlay xr/xi (dead after proj)
  float* Oi_ = (float*)(wsb + ((size_t)24 << 20));
  float* out = (float*)d_out;

  hipLaunchKernelGGL(dft2_fwd_kernel, dim3(512), dim3(256), 0, stream,
                     x, y, xr, xi, yr, yi);
  hipLaunchKernelGGL(proj_pack_kernel, dim3(64, 3, 2), dim3(256), 0, stream,
                     xr, xi, yr, yi,
                     Wqr, bqr, Wqi, bqi, Wkr, bkr, Wki, bki, Wvr, bvr, Wvi, bvi,
                     Qpk, Kpk, Vpk);
  hipLaunchKernelGGL(attn_mfma_kernel, dim3(128, 2), dim3(256), 0, stream,
                     (const short*)Qpk, (const short*)Kpk, (const short*)Vpk, Or_, Oi_);
  hipLaunchKernelGGL(idft2_kernel, dim3(256), dim3(256), 0, stream,
                     Or_, Oi_, out);
}

// Round 3
// 480.000 us; speedup vs baseline: 3.9802x; 1.0263x over previous
//
#include <hip/hip_runtime.h>
#include <math.h>

// B=2, C=128, H=W=64, N=4096.
// ws layout (bytes):
//   [0,8M)   Qpk  bf16 frag-packed  [b][tq(256)][a(4)][s(4)][l(64)][j(8)]
//   [8M,16M) Kpk  bf16 frag-packed  [b][mt(64)][a(4)][tml(4)][s(4)][l(64)][j(8)]  (64KB per (b,mt))
//   [16M,20M)Vpk  bf16 frag-packed  [b][sm(128)][tc(16)][l(64)][j(8)]  (cc: 0-127=Vr,128-255=Vi)
//   [20M,36M) spectra xr,xi,yr,yi fp32 (phase1-2); Or,Oi fp32 overlay [20M,28M) (phase4-5)
// a: 0=hi(re),1=lo(re),2=hi(im),3=lo(im). frag map: lane l holds X[row=l&15][k=32s+8*(l>>4)+j]

#define PI2 6.283185307179586f

typedef __attribute__((ext_vector_type(8))) short short8;
typedef __attribute__((ext_vector_type(4))) float f32x4;

#define MFMA16(A,B,C) __builtin_amdgcn_mfma_f32_16x16x32_bf16((A),(B),(C),0,0,0)

__device__ inline unsigned short f2bf(float x){
  union{float f; unsigned int u;} a; a.f = x;
  unsigned int r = (a.u + 0x7fffu + ((a.u>>16)&1u)) >> 16;
  return (unsigned short)r;
}
__device__ inline float bf2f(unsigned short h){
  union{unsigned int u; float f;} a; a.u = ((unsigned int)h)<<16; return a.f;
}
__device__ inline short8 neg8(short8 x){
  union{short8 v; unsigned int u[4];} a; a.v = x;
  a.u[0]^=0x80008000u; a.u[1]^=0x80008000u; a.u[2]^=0x80008000u; a.u[3]^=0x80008000u;
  return a.v;
}
__device__ inline void gload_lds16(const void* g, void* lds){
  __builtin_amdgcn_global_load_lds((const __attribute__((address_space(1))) unsigned int*)g,
                                   (__attribute__((address_space(3))) unsigned int*)lds,
                                   16, 0, 0);
}

// ---------------------------------------------------------------------------
// Kernel 1: forward DFT2 of x and y (two 64-pt DFT stages per (b,c) plane)
// ---------------------------------------------------------------------------
__global__ __launch_bounds__(256) void dft2_fwd_kernel(
    const float* __restrict__ x, const float* __restrict__ y,
    float* __restrict__ xr, float* __restrict__ xi,
    float* __restrict__ yr, float* __restrict__ yi)
{
  __shared__ float Xs[4096];
  __shared__ float Tr[4096], Ti[4096];
  __shared__ float twc[64], tws[64];
  int blk = blockIdx.x;
  const float* src; float *outr, *outi;
  int plane;
  if (blk < 256) { src = x; outr = xr; outi = xi; plane = blk; }
  else           { src = y; outr = yr; outi = yi; plane = blk - 256; }
  int b = plane >> 7, c = plane & 127;
  int t = threadIdx.x;
  if (t < 64) {
    float ang = -PI2 * (float)t / 64.0f;
    twc[t] = cosf(ang); tws[t] = sinf(ang);
  }
  const float* p = src + ((size_t)plane << 12);
  for (int i = t; i < 4096; i += 256) Xs[i] = p[i];
  __syncthreads();
  for (int j = 0; j < 16; j++) {
    int o = t + 256 * j; int h = o >> 6, wp = o & 63;
    float ar = 0.f, ai = 0.f;
    for (int w = 0; w < 64; w++) {
      int k = (w * wp) & 63;
      float v = Xs[h * 64 + w];
      ar = fmaf(v, twc[k], ar);
      ai = fmaf(v, tws[k], ai);
    }
    Tr[h * 64 + wp] = ar; Ti[h * 64 + wp] = ai;
  }
  __syncthreads();
  size_t ob = ((size_t)b * 4096) * 128 + c;
  for (int j = 0; j < 16; j++) {
    int o = t + 256 * j; int hp = o >> 6, wp = o & 63;
    float ar = 0.f, ai = 0.f;
    for (int h = 0; h < 64; h++) {
      int k = (h * hp) & 63;
      float cr = twc[k], ci = tws[k];
      float tr = Tr[h * 64 + wp], ti = Ti[h * 64 + wp];
      ar += tr * cr - ti * ci;
      ai += tr * ci + ti * cr;
    }
    int n = (hp << 6) + wp;
    outr[ob + (size_t)n * 128] = ar;
    outi[ob + (size_t)n * 128] = ai;
  }
}

// ---------------------------------------------------------------------------
// Kernel 2: complex projections; bf16 frag packs staged in LDS, coalesced dump
// ---------------------------------------------------------------------------
__global__ __launch_bounds__(256) void proj_pack_kernel(
    const float* __restrict__ xr, const float* __restrict__ xi,
    const float* __restrict__ yr, const float* __restrict__ yi,
    const float* __restrict__ Wqr, const float* __restrict__ bqr,
    const float* __restrict__ Wqi, const float* __restrict__ bqi,
    const float* __restrict__ Wkr, const float* __restrict__ bkr,
    const float* __restrict__ Wki, const float* __restrict__ bki,
    const float* __restrict__ Wvr, const float* __restrict__ bvr,
    const float* __restrict__ Wvi, const float* __restrict__ bvi,
    unsigned short* __restrict__ Qpk, unsigned short* __restrict__ Kpk,
    unsigned short* __restrict__ Vpk)
{
  __shared__ __align__(16) char smem[65536];
  float* Asr = (float*)smem;              // 64*33
  float* Asi = Asr + 64 * 33;
  float* Wsr = Asi + 64 * 33;             // 128*33
  float* Wsi = Wsr + 128 * 33;            // total 50688 B
  unsigned short* pk = (unsigned short*)smem;  // phase-2 overlay (64 KB)

  int nt = blockIdx.x, lin = blockIdx.y, b = blockIdx.z;
  const float *ar, *ai, *Wr, *Wi, *br_, *bi_;
  if (lin == 0)      { ar = xr; ai = xi; Wr = Wqr; Wi = Wqi; br_ = bqr; bi_ = bqi; }
  else if (lin == 1) { ar = yr; ai = yi; Wr = Wkr; Wi = Wki; br_ = bkr; bi_ = bki; }
  else               { ar = yr; ai = yi; Wr = Wvr; Wi = Wvi; br_ = bvr; bi_ = bvi; }
  int t = threadIdx.x; int td = t & 15, tn = t >> 4;
  int n0 = nt * 64;
  size_t abase = (size_t)b * 4096 * 128 + (size_t)n0 * 128;
  float accr[4][8] = {}, acci[4][8] = {};
  for (int kk = 0; kk < 4; kk++) {
    __syncthreads();
    for (int idx = t; idx < 64 * 32; idx += 256) {
      int r = idx >> 5, ccol = idx & 31;
      Asr[r * 33 + ccol] = ar[abase + (size_t)r * 128 + kk * 32 + ccol];
      Asi[r * 33 + ccol] = ai[abase + (size_t)r * 128 + kk * 32 + ccol];
    }
    for (int idx = t; idx < 128 * 32; idx += 256) {
      int r = idx >> 5, ccol = idx & 31;
      Wsr[r * 33 + ccol] = Wr[(size_t)r * 128 + kk * 32 + ccol];
      Wsi[r * 33 + ccol] = Wi[(size_t)r * 128 + kk * 32 + ccol];
    }
    __syncthreads();
    for (int k = 0; k < 32; k++) {
      float a_r[4], a_i[4], w_r[8], w_i[8];
      #pragma unroll
      for (int i = 0; i < 4; i++) {
        a_r[i] = Asr[(tn * 4 + i) * 33 + k];
        a_i[i] = Asi[(tn * 4 + i) * 33 + k];
      }
      #pragma unroll
      for (int jj = 0; jj < 8; jj++) {
        w_r[jj] = Wsr[(td + 16 * jj) * 33 + k];
        w_i[jj] = Wsi[(td + 16 * jj) * 33 + k];
      }
      #pragma unroll
      for (int i = 0; i < 4; i++)
        #pragma unroll
        for (int jj = 0; jj < 8; jj++) {
          accr[i][jj] += a_r[i] * w_r[jj] - a_i[i] * w_i[jj];
          acci[i][jj] += a_i[i] * w_r[jj] + a_r[i] * w_i[jj];
        }
    }
  }
  __syncthreads();   // done with tile buffers; smem becomes the pack buffer
  // ---- pack into LDS (scattered b16 LDS writes, cheap) ----
  for (int jj = 0; jj < 8; jj++) {
    int d = td + 16 * jj;
    float brd = br_[d], bid = bi_[d];
    #pragma unroll
    for (int i = 0; i < 4; i++) {
      int n = n0 + tn * 4 + i;
      float cr = accr[i][jj] + (brd - bid);
      float ci = acci[i][jj] + (brd + bid);
      if (lin <= 1) {
        unsigned short rh = f2bf(cr); unsigned short rl = f2bf(cr - bf2f(rh));
        unsigned short ih = f2bf(ci); unsigned short il = f2bf(ci - bf2f(ih));
        int s = d >> 5, j = d & 7;
        int lq = ((d & 31) >> 3) * 16 + (n & 15);
        int gi = (n >> 4) & 3;
        if (lin == 0) {
          // LDS layout [gi][a][s][l][j]
          pk[(((gi * 4 + 0) * 4 + s) * 512) + lq * 8 + j] = rh;
          pk[(((gi * 4 + 1) * 4 + s) * 512) + lq * 8 + j] = rl;
          pk[(((gi * 4 + 2) * 4 + s) * 512) + lq * 8 + j] = ih;
          pk[(((gi * 4 + 3) * 4 + s) * 512) + lq * 8 + j] = il;
        } else {
          // LDS layout [a][tml=gi][s][l][j]  (matches global K layout)
          pk[(((0 * 4 + gi) * 4 + s) * 512) + lq * 8 + j] = rh;
          pk[(((1 * 4 + gi) * 4 + s) * 512) + lq * 8 + j] = rl;
          pk[(((2 * 4 + gi) * 4 + s) * 512) + lq * 8 + j] = ih;
          pk[(((3 * 4 + gi) * 4 + s) * 512) + lq * 8 + j] = il;
        }
      } else {
        int smi = (n >> 5) & 1, jv = n & 7;
        int lv = ((n & 31) >> 3) * 16 + (d & 15);
        // LDS layout [smi][tc][l][j]
        pk[(smi * 16 + (d >> 4)) * 512 + lv * 8 + jv] = f2bf(cr);
        pk[(smi * 16 + 8 + (d >> 4)) * 512 + lv * 8 + jv] = f2bf(ci);
      }
    }
  }
  __syncthreads();
  // ---- coalesced dump ----
  if (lin == 0) {
    int tq0 = nt * 4;
    #pragma unroll
    for (int ch = 0; ch < 16; ch++) {
      int idx = t + 256 * ch;          // short8 index
      int l = idx & 63; int rest = idx >> 6;
      int s = rest & 3, a = (rest >> 2) & 3, gi = rest >> 4;
      short8 v = *(const short8*)(pk + (size_t)idx * 8);
      size_t gaddr = ((size_t)((b * 256 + tq0 + gi) * 16 + a * 4 + s)) * 512 + (size_t)l * 8;
      *(short8*)(Qpk + gaddr) = v;
    }
  } else if (lin == 1) {
    int mt2 = n0 >> 6;
    size_t gbase = ((size_t)(b * 64 + mt2)) * 32768;
    #pragma unroll
    for (int ch = 0; ch < 16; ch++) {
      int idx = t + 256 * ch;
      short8 v = *(const short8*)(pk + (size_t)idx * 8);
      *(short8*)(Kpk + gbase + (size_t)idx * 8) = v;
    }
  } else {
    int sm0 = n0 >> 5;
    size_t gbase = ((size_t)(b * 128 + sm0)) * 8192;
    #pragma unroll
    for (int ch = 0; ch < 8; ch++) {
      int idx = t + 256 * ch;
      short8 v = *(const short8*)(pk + (size_t)idx * 8);
      *(short8*)(Vpk + gbase + (size_t)idx * 8) = v;
    }
  }
}

// ---------------------------------------------------------------------------
// Kernel 3: MFMA flash attention, 8 waves (512 thr): wave = qg(2) x mh(4).
// QBLK=32, KBLK=64. K dbuf in LDS via global_load_lds; V direct from global.
// Split-bf16 scores: hh+hl+lh (12 MFMA per 16x16x(K=128) quadrant pair).
// ---------------------------------------------------------------------------
__global__ __launch_bounds__(512, 1) void attn_mfma_kernel(
    const short* __restrict__ Qpk, const short* __restrict__ Kpk,
    const short* __restrict__ Vpk,
    float* __restrict__ Or_, float* __restrict__ Oi_)
{
  __shared__ __align__(16) short Klds[2][32768];
  __shared__ __align__(16) short Pfrag[4 * 512];
  __shared__ float rmax[2][16][4];
  __shared__ float rsum[2][16][4];

  const int bi = blockIdx.x;
  const int xg = bi & 7;
  const int b = xg >> 2;                      // XCDs 0-3 -> b=0, 4-7 -> b=1
  const int qt = (bi >> 3) * 4 + (xg & 3);
  const int t = threadIdx.x;
  const int w = t >> 6, l = t & 63;
  const int qg = w & 1, mh = w >> 1;          // mh 0..3: 16-col quarter of KBLK
  const int g = l >> 4, c = l & 15;

  const short8* Qp8 = (const short8*)Qpk;
  const int tq = qt * 2 + qg;
  short8 Qf[4][4];
  #pragma unroll
  for (int a = 0; a < 4; a++)
    #pragma unroll
    for (int s = 0; s < 4; s++)
      Qf[a][s] = Qp8[((size_t)((b * 256 + tq) * 16 + a * 4 + s)) * 64 + l];

  f32x4 O[4], M, L;
  #pragma unroll
  for (int nt = 0; nt < 4; nt++) O[nt] = (f32x4){0.f, 0.f, 0.f, 0.f};
  M = (f32x4){-3e38f, -3e38f, -3e38f, -3e38f};
  L = (f32x4){0.f, 0.f, 0.f, 0.f};

  const char* Kg = (const char*)Kpk;
  {
    const char* gsrc = Kg + ((size_t)(b * 64) << 16);
    char* lb = (char*)&Klds[0][0];
    #pragma unroll
    for (int i2 = 0; i2 < 8; i2++) {
      int ch = i2 * 8 + w;
      gload_lds16(gsrc + ch * 1024 + l * 16, lb + ch * 1024);
    }
  }
  const short8* Vp8 = (const short8*)Vpk;

  for (int mt = 0; mt < 64; mt++) {
    const int cur = mt & 1;
    __syncthreads();                 // drains vmcnt -> Klds[cur] ready; Pfrag free
    if (mt + 1 < 64) {
      const char* gsrc = Kg + ((size_t)(b * 64 + mt + 1) << 16);
      char* lb = (char*)&Klds[cur ^ 1][0];
      #pragma unroll
      for (int i2 = 0; i2 < 8; i2++) {
        int ch = i2 * 8 + w;
        gload_lds16(gsrc + ch * 1024 + l * 16, lb + ch * 1024);
      }
    }
    // ---- QK^T quadrant (16 q rows x 16 m cols), split bf16 ----
    const short8* kb8 = (const short8*)&Klds[cur][0];
    f32x4 sr = (f32x4){0,0,0,0}, si = (f32x4){0,0,0,0};
    #pragma unroll
    for (int s = 0; s < 4; s++) {
      short8 Brh = kb8[((0 * 4 + mh) * 4 + s) * 64 + l];
      short8 Brl = kb8[((1 * 4 + mh) * 4 + s) * 64 + l];
      short8 Bih = kb8[((2 * 4 + mh) * 4 + s) * 64 + l];
      short8 Bil = kb8[((3 * 4 + mh) * 4 + s) * 64 + l];
      short8 nBih = neg8(Bih), nBil = neg8(Bil);
      sr = MFMA16(Qf[0][s], Brh, sr);   // Qrh*Krh
      si = MFMA16(Qf[0][s], Bih, si);   // Qrh*Kih
      sr = MFMA16(Qf[1][s], Brh, sr);   // Qrl*Krh
      si = MFMA16(Qf[1][s], Bih, si);   // Qrl*Kih
      sr = MFMA16(Qf[0][s], Brl, sr);   // Qrh*Krl
      si = MFMA16(Qf[0][s], Bil, si);   // Qrh*Kil
      sr = MFMA16(Qf[2][s], nBih, sr);  // -Qih*Kih
      si = MFMA16(Qf[2][s], Brh, si);   // Qih*Krh
      sr = MFMA16(Qf[3][s], nBih, sr);  // -Qil*Kih
      si = MFMA16(Qf[3][s], Brh, si);   // Qil*Krh
      sr = MFMA16(Qf[2][s], nBil, sr);  // -Qih*Kil
      si = MFMA16(Qf[2][s], Brl, si);   // Qih*Krl
    }
    // ---- scores + online softmax (row spans 4 mh-waves) ----
    f32x4 s0, mx;
    #pragma unroll
    for (int r = 0; r < 4; r++) {
      s0[r] = sqrtf(sr[r] * sr[r] + si[r] * si[r] + 1e-8f);
      mx[r] = s0[r];
    }
    #pragma unroll
    for (int d = 1; d < 16; d <<= 1) {
      #pragma unroll
      for (int r = 0; r < 4; r++) mx[r] = fmaxf(mx[r], __shfl_xor(mx[r], d));
    }
    if (c < 4) rmax[qg][4 * g + c][mh] = mx[c];
    __syncthreads();
    f32x4 nm, esc, p, ps;
    #pragma unroll
    for (int r = 0; r < 4; r++) {
      float v = fmaxf(fmaxf(rmax[qg][4 * g + r][0], rmax[qg][4 * g + r][1]),
                      fmaxf(rmax[qg][4 * g + r][2], rmax[qg][4 * g + r][3]));
      nm[r] = fmaxf(M[r], v);
      esc[r] = __expf(M[r] - nm[r]);
      M[r] = nm[r];
      p[r] = __expf(s0[r] - nm[r]);
      ps[r] = p[r];
    }
    #pragma unroll
    for (int d = 1; d < 16; d <<= 1) {
      #pragma unroll
      for (int r = 0; r < 4; r++) ps[r] += __shfl_xor(ps[r], d);
    }
    if (c < 4) rsum[qg][4 * g + c][mh] = ps[c];
    {
      int ks = mh >> 1;
      int lb2 = ((mh & 1) * 2 + (c >> 3)) * 16;
      int j = c & 7;
      #pragma unroll
      for (int r = 0; r < 4; r++)
        Pfrag[(qg * 2 + ks) * 512 + (lb2 + 4 * g + r) * 8 + j] = (short)f2bf(p[r]);
    }
    __syncthreads();
    #pragma unroll
    for (int r = 0; r < 4; r++) {
      L[r] = L[r] * esc[r] + rsum[qg][4 * g + r][0] + rsum[qg][4 * g + r][1]
                           + rsum[qg][4 * g + r][2] + rsum[qg][4 * g + r][3];
      #pragma unroll
      for (int nt = 0; nt < 4; nt++) O[nt][r] *= esc[r];
    }
    // ---- PV: wave's cc quarter = mh*64 .. mh*64+63 ----
    #pragma unroll
    for (int ks = 0; ks < 2; ks++) {
      short8 Pa = *(const short8*)&Pfrag[(qg * 2 + ks) * 512 + l * 8];
      const size_t vb = ((size_t)((b * 128 + mt * 2 + ks) * 16 + mh * 4)) * 64 + l;
      #pragma unroll
      for (int nt = 0; nt < 4; nt++) {
        short8 Vb = Vp8[vb + (size_t)nt * 64];
        O[nt] = MFMA16(Pa, Vb, O[nt]);
      }
    }
  }
  // ---- normalize + write out ----
  const size_t base = (size_t)b * 4096 * 128;
  f32x4 inv;
  #pragma unroll
  for (int r = 0; r < 4; r++) inv[r] = 1.0f / L[r];
  #pragma unroll
  for (int nt = 0; nt < 4; nt++) {
    int cc = mh * 64 + nt * 16 + c;
    #pragma unroll
    for (int r = 0; r < 4; r++) {
      int row = qt * 32 + qg * 16 + 4 * g + r;
      float v = O[nt][r] * inv[r];
      if (cc < 128) Or_[base + (size_t)row * 128 + cc] = v;
      else          Oi_[base + (size_t)row * 128 + cc - 128] = v;
    }
  }
}

// ---------------------------------------------------------------------------
// Kernel 4: inverse DFT2 (real part), output [b][c][h][w]
// ---------------------------------------------------------------------------
__global__ __launch_bounds__(256) void idft2_kernel(
    const float* __restrict__ Or_, const float* __restrict__ Oi_,
    float* __restrict__ out)
{
  __shared__ float Ar[4096], Ai[4096], Tr[4096], Ti[4096];
  __shared__ float twc[64], tws[64];
  int plane = blockIdx.x; int b = plane >> 7, c = plane & 127;
  int t = threadIdx.x;
  if (t < 64) {
    float ang = PI2 * (float)t / 64.0f;
    twc[t] = cosf(ang); tws[t] = sinf(ang);
  }
  size_t ibase = (size_t)b * 4096 * 128 + c;
  for (int i = t; i < 4096; i += 256) {
    Ar[i] = Or_[ibase + (size_t)i * 128];
    Ai[i] = Oi_[ibase + (size_t)i * 128];
  }
  __syncthreads();
  for (int j = 0; j < 16; j++) {
    int o = t + 256 * j; int hp = o >> 6, w = o & 63;
    float tr = 0.f, ti = 0.f;
    for (int wp = 0; wp < 64; wp++) {
      int k = (wp * w) & 63;
      float cr = twc[k], ci = tws[k];
      float ar = Ar[hp * 64 + wp], ai = Ai[hp * 64 + wp];
      tr += ar * cr - ai * ci;
      ti += ai * cr + ar * ci;
    }
    Tr[hp * 64 + w] = tr; Ti[hp * 64 + w] = ti;
  }
  __syncthreads();
  size_t obase = ((size_t)plane) << 12;
  for (int j = 0; j < 16; j++) {
    int o = t + 256 * j; int h = o >> 6, w = o & 63;
    float acc = 0.f;
    for (int hp = 0; hp < 64; hp++) {
      int k = (hp * h) & 63;
      acc += Tr[hp * 64 + w] * twc[k] - Ti[hp * 64 + w] * tws[k];
    }
    out[obase + o] = acc * (1.0f / 4096.0f);
  }
}

extern "C" void kernel_launch(void* const* d_in, const int* in_sizes, int n_in,
                              void* d_out, int out_size, void* d_ws, size_t ws_size,
                              hipStream_t stream) {
  const float* x   = (const float*)d_in[0];
  const float* y   = (const float*)d_in[1];
  const float* Wqr = (const float*)d_in[2];  const float* bqr = (const float*)d_in[3];
  const float* Wqi = (const float*)d_in[4];  const float* bqi = (const float*)d_in[5];
  const float* Wkr = (const float*)d_in[6];  const float* bkr = (const float*)d_in[7];
  const float* Wki = (const float*)d_in[8];  const float* bki = (const float*)d_in[9];
  const float* Wvr = (const float*)d_in[10]; const float* bvr = (const float*)d_in[11];
  const float* Wvi = (const float*)d_in[12]; const float* bvi = (const float*)d_in[13];
  char* wsb = (char*)d_ws;
  if (ws_size < ((size_t)36 << 20)) return;  // need 36 MiB
  unsigned short* Qpk = (unsigned short*)(wsb);
  unsigned short* Kpk = (unsigned short*)(wsb + ((size_t)8 << 20));
  unsigned short* Vpk = (unsigned short*)(wsb + ((size_t)16 << 20));
  float* xr = (float*)(wsb + ((size_t)20 << 20));
  float* xi = (float*)(wsb + ((size_t)24 << 20));
  float* yr = (float*)(wsb + ((size_t)28 << 20));
  float* yi = (float*)(wsb + ((size_t)32 << 20));
  float* Or_ = (float*)(wsb + ((size_t)20 << 20));  // overlay xr/xi (dead after proj)
  float* Oi_ = (float*)(wsb + ((size_t)24 << 20));
  float* out = (float*)d_out;

  hipLaunchKernelGGL(dft2_fwd_kernel, dim3(512), dim3(256), 0, stream,
                     x, y, xr, xi, yr, yi);
  hipLaunchKernelGGL(proj_pack_kernel, dim3(64, 3, 2), dim3(256), 0, stream,
                     xr, xi, yr, yi,
                     Wqr, bqr, Wqi, bqi, Wkr, bkr, Wki, bki, Wvr, bvr, Wvi, bvi,
                     Qpk, Kpk, Vpk);
  hipLaunchKernelGGL(attn_mfma_kernel, dim3(256), dim3(512), 0, stream,
                     (const short*)Qpk, (const short*)Kpk, (const short*)Vpk, Or_, Oi_);
  hipLaunchKernelGGL(idft2_kernel, dim3(256), dim3(256), 0, stream,
                     Or_, Oi_, out);
}

// Round 4
// 462.392 us; speedup vs baseline: 4.1318x; 1.0381x over previous
//
#include <hip/hip_runtime.h>
#include <math.h>

// B=2, C=128, H=W=64, N=4096.
// ws layout (bytes):
//   [0,8M)   Qpk  bf16 frag-packed  [b][tq(256)][a(4)][s(4)][l(64)][j(8)]
//   [8M,16M) Kpk  bf16 frag-packed  [b][mt(64)][a(4)][tml(4)][s(4)][l(64)][j(8)]  (64KB per (b,mt))
//   [16M,20M)Vpk  bf16 frag-packed  [b][sm(128)][tc(16)][l(64)][j(8)]  (cc: 0-127=Vr,128-255=Vi)
//   [20M,36M) spectra xr,xi,yr,yi fp32 (phase1-2); Or,Oi fp32 overlay [20M,28M) (phase4-5)
// a: 0=hi(re),1=lo(re),2=hi(im),3=lo(im). frag map: lane l holds X[row=l&15][k=32s+8*(l>>4)+j]

#define PI2 6.283185307179586f

typedef __attribute__((ext_vector_type(8))) short short8;
typedef __attribute__((ext_vector_type(4))) float f32x4;

#define MFMA16(A,B,C) __builtin_amdgcn_mfma_f32_16x16x32_bf16((A),(B),(C),0,0,0)

__device__ inline unsigned short f2bf(float x){
  union{float f; unsigned int u;} a; a.f = x;
  unsigned int r = (a.u + 0x7fffu + ((a.u>>16)&1u)) >> 16;
  return (unsigned short)r;
}
__device__ inline float bf2f(unsigned short h){
  union{unsigned int u; float f;} a; a.u = ((unsigned int)h)<<16; return a.f;
}
__device__ inline short8 neg8(short8 x){
  union{short8 v; unsigned int u[4];} a; a.v = x;
  a.u[0]^=0x80008000u; a.u[1]^=0x80008000u; a.u[2]^=0x80008000u; a.u[3]^=0x80008000u;
  return a.v;
}
__device__ inline void gload_lds16(const void* g, void* lds){
  __builtin_amdgcn_global_load_lds((const __attribute__((address_space(1))) unsigned int*)g,
                                   (__attribute__((address_space(3))) unsigned int*)lds,
                                   16, 0, 0);
}

// ---------------------------------------------------------------------------
// Kernel 1: forward DFT2 of x and y (two 64-pt DFT stages per (b,c) plane)
// ---------------------------------------------------------------------------
__global__ __launch_bounds__(256) void dft2_fwd_kernel(
    const float* __restrict__ x, const float* __restrict__ y,
    float* __restrict__ xr, float* __restrict__ xi,
    float* __restrict__ yr, float* __restrict__ yi)
{
  __shared__ float Xs[4096];
  __shared__ float Tr[4096], Ti[4096];
  __shared__ float twc[64], tws[64];
  int blk = blockIdx.x;
  const float* src; float *outr, *outi;
  int plane;
  if (blk < 256) { src = x; outr = xr; outi = xi; plane = blk; }
  else           { src = y; outr = yr; outi = yi; plane = blk - 256; }
  int b = plane >> 7, c = plane & 127;
  int t = threadIdx.x;
  if (t < 64) {
    float ang = -PI2 * (float)t / 64.0f;
    twc[t] = cosf(ang); tws[t] = sinf(ang);
  }
  const float* p = src + ((size_t)plane << 12);
  for (int i = t; i < 4096; i += 256) Xs[i] = p[i];
  __syncthreads();
  for (int j = 0; j < 16; j++) {
    int o = t + 256 * j; int h = o >> 6, wp = o & 63;
    float ar = 0.f, ai = 0.f;
    for (int w = 0; w < 64; w++) {
      int k = (w * wp) & 63;
      float v = Xs[h * 64 + w];
      ar = fmaf(v, twc[k], ar);
      ai = fmaf(v, tws[k], ai);
    }
    Tr[h * 64 + wp] = ar; Ti[h * 64 + wp] = ai;
  }
  __syncthreads();
  size_t ob = ((size_t)b * 4096) * 128 + c;
  for (int j = 0; j < 16; j++) {
    int o = t + 256 * j; int hp = o >> 6, wp = o & 63;
    float ar = 0.f, ai = 0.f;
    for (int h = 0; h < 64; h++) {
      int k = (h * hp) & 63;
      float cr = twc[k], ci = tws[k];
      float tr = Tr[h * 64 + wp], ti = Ti[h * 64 + wp];
      ar += tr * cr - ti * ci;
      ai += tr * ci + ti * cr;
    }
    int n = (hp << 6) + wp;
    outr[ob + (size_t)n * 128] = ar;
    outi[ob + (size_t)n * 128] = ai;
  }
}

// ---------------------------------------------------------------------------
// Kernel 2 (x3 via template): complex projection + bf16 frag pack.
// Split per LIN so each kernel's regalloc is clean (suspected spills when the
// 3-way branchy epilogue shared one kernel). float4 LDS tiles, stride 36.
// ---------------------------------------------------------------------------
template<int LIN>
__global__ __launch_bounds__(256) void proj_pack_t(
    const float* __restrict__ ar, const float* __restrict__ ai,
    const float* __restrict__ Wr, const float* __restrict__ Wi,
    const float* __restrict__ br_, const float* __restrict__ bi_,
    unsigned short* __restrict__ outp)
{
  __shared__ __align__(16) char smem[65536];
  float* Asr = (float*)smem;                 // [64][36]
  float* Asi = Asr + 64 * 36;
  float* Wsr = Asi + 64 * 36;                // [128][36]
  float* Wsi = Wsr + 128 * 36;               // ends at 55296 B
  unsigned short* pk = (unsigned short*)smem;  // phase-2 overlay (64 KB)

  int nt = blockIdx.x, b = blockIdx.y;
  int t = threadIdx.x; int td = t & 15, tn = t >> 4;
  int n0 = nt * 64;
  size_t abase = (size_t)b * 4096 * 128 + (size_t)n0 * 128;
  float accr[4][8] = {}, acci[4][8] = {};
  for (int kk = 0; kk < 4; kk++) {
    __syncthreads();
    #pragma unroll
    for (int q2 = 0; q2 < 2; q2++) {
      int idx = t + 256 * q2; int r = idx >> 3, c4 = (idx & 7) * 4;
      f32x4 va = *(const f32x4*)&ar[abase + (size_t)r * 128 + kk * 32 + c4];
      f32x4 vb = *(const f32x4*)&ai[abase + (size_t)r * 128 + kk * 32 + c4];
      *(f32x4*)&Asr[r * 36 + c4] = va;
      *(f32x4*)&Asi[r * 36 + c4] = vb;
    }
    #pragma unroll
    for (int q2 = 0; q2 < 4; q2++) {
      int idx = t + 256 * q2; int r = idx >> 3, c4 = (idx & 7) * 4;
      f32x4 va = *(const f32x4*)&Wr[(size_t)r * 128 + kk * 32 + c4];
      f32x4 vb = *(const f32x4*)&Wi[(size_t)r * 128 + kk * 32 + c4];
      *(f32x4*)&Wsr[r * 36 + c4] = va;
      *(f32x4*)&Wsi[r * 36 + c4] = vb;
    }
    __syncthreads();
    for (int k4 = 0; k4 < 8; k4++) {
      f32x4 a_r[4], a_i[4], w_r[8], w_i[8];
      #pragma unroll
      for (int i = 0; i < 4; i++) {
        a_r[i] = *(const f32x4*)&Asr[(tn * 4 + i) * 36 + k4 * 4];
        a_i[i] = *(const f32x4*)&Asi[(tn * 4 + i) * 36 + k4 * 4];
      }
      #pragma unroll
      for (int jj = 0; jj < 8; jj++) {
        w_r[jj] = *(const f32x4*)&Wsr[(td + 16 * jj) * 36 + k4 * 4];
        w_i[jj] = *(const f32x4*)&Wsi[(td + 16 * jj) * 36 + k4 * 4];
      }
      #pragma unroll
      for (int i = 0; i < 4; i++)
        #pragma unroll
        for (int jj = 0; jj < 8; jj++)
          #pragma unroll
          for (int e = 0; e < 4; e++) {
            accr[i][jj] += a_r[i][e] * w_r[jj][e] - a_i[i][e] * w_i[jj][e];
            acci[i][jj] += a_i[i][e] * w_r[jj][e] + a_r[i][e] * w_i[jj][e];
          }
    }
  }
  __syncthreads();   // tile buffers dead; smem becomes the pack buffer
  for (int jj = 0; jj < 8; jj++) {
    int d = td + 16 * jj;
    float brd = br_[d], bid = bi_[d];
    #pragma unroll
    for (int i = 0; i < 4; i++) {
      int n = n0 + tn * 4 + i;
      float cr = accr[i][jj] + (brd - bid);
      float ci = acci[i][jj] + (brd + bid);
      if constexpr (LIN <= 1) {
        unsigned short rh = f2bf(cr); unsigned short rl = f2bf(cr - bf2f(rh));
        unsigned short ih = f2bf(ci); unsigned short il = f2bf(ci - bf2f(ih));
        int s = d >> 5, j = d & 7;
        int lq = ((d & 31) >> 3) * 16 + (n & 15);
        int gi = (n >> 4) & 3;
        if constexpr (LIN == 0) {
          pk[(((gi * 4 + 0) * 4 + s) * 512) + lq * 8 + j] = rh;
          pk[(((gi * 4 + 1) * 4 + s) * 512) + lq * 8 + j] = rl;
          pk[(((gi * 4 + 2) * 4 + s) * 512) + lq * 8 + j] = ih;
          pk[(((gi * 4 + 3) * 4 + s) * 512) + lq * 8 + j] = il;
        } else {
          pk[(((0 * 4 + gi) * 4 + s) * 512) + lq * 8 + j] = rh;
          pk[(((1 * 4 + gi) * 4 + s) * 512) + lq * 8 + j] = rl;
          pk[(((2 * 4 + gi) * 4 + s) * 512) + lq * 8 + j] = ih;
          pk[(((3 * 4 + gi) * 4 + s) * 512) + lq * 8 + j] = il;
        }
      } else {
        int smi = (n >> 5) & 1, jv = n & 7;
        int lv = ((n & 31) >> 3) * 16 + (d & 15);
        pk[(smi * 16 + (d >> 4)) * 512 + lv * 8 + jv] = f2bf(cr);
        pk[(smi * 16 + 8 + (d >> 4)) * 512 + lv * 8 + jv] = f2bf(ci);
      }
    }
  }
  __syncthreads();
  if constexpr (LIN == 0) {
    int tq0 = nt * 4;
    #pragma unroll
    for (int ch = 0; ch < 16; ch++) {
      int idx = t + 256 * ch;
      int l = idx & 63; int rest = idx >> 6;
      int s = rest & 3, a = (rest >> 2) & 3, gi = rest >> 4;
      short8 v = *(const short8*)(pk + (size_t)idx * 8);
      size_t gaddr = ((size_t)((b * 256 + tq0 + gi) * 16 + a * 4 + s)) * 512 + (size_t)l * 8;
      *(short8*)(outp + gaddr) = v;
    }
  } else if constexpr (LIN == 1) {
    size_t gbase = ((size_t)(b * 64 + (n0 >> 6))) * 32768;
    #pragma unroll
    for (int ch = 0; ch < 16; ch++) {
      int idx = t + 256 * ch;
      short8 v = *(const short8*)(pk + (size_t)idx * 8);
      *(short8*)(outp + gbase + (size_t)idx * 8) = v;
    }
  } else {
    size_t gbase = ((size_t)(b * 128 + (n0 >> 5))) * 8192;
    #pragma unroll
    for (int ch = 0; ch < 8; ch++) {
      int idx = t + 256 * ch;
      short8 v = *(const short8*)(pk + (size_t)idx * 8);
      *(short8*)(outp + gbase + (size_t)idx * 8) = v;
    }
  }
}

// ---------------------------------------------------------------------------
// Kernel 3: MFMA flash attention, swapped QK^T (A=K from LDS, B=Q in regs),
// pipelined PV (PV of tile t-1 overlaps QK of tile t), L via ones-col MFMA.
// 8 waves: qg = w&1 (16 q rows), ms = w>>1 (16-col m-slice / 64-col cc-slice).
// 2 barriers per iter.  Scores land transposed: lane holds 4 m for q=c.
// ---------------------------------------------------------------------------
__global__ __launch_bounds__(512, 1) void attn_mfma_kernel(
    const short* __restrict__ Qpk, const short* __restrict__ Kpk,
    const short* __restrict__ Vpk,
    float* __restrict__ Or_, float* __restrict__ Oi_)
{
  __shared__ __align__(16) short Klds[2][32768];
  __shared__ __align__(16) short Pfrag[2 * 16 * 72];   // [qg][q][64m + 8 pad]
  __shared__ __align__(16) float rmax[2][16][4];       // [qg][q][ms]
  __shared__ __align__(16) float escs[2][16];          // [qg][q]

  const int bi = blockIdx.x;
  const int xg = bi & 7;
  const int b = xg >> 2;                      // XCDs 0-3 -> b=0, 4-7 -> b=1
  const int qt = (bi >> 3) * 4 + (xg & 3);
  const int t = threadIdx.x;
  const int w = t >> 6, l = t & 63;
  const int qg = w & 1, ms = w >> 1;
  const int g = l >> 4, c = l & 15;

  // Q fragments (used as MFMA B operands)
  const short8* Qp8 = (const short8*)Qpk;
  const int tq = qt * 2 + qg;
  short8 Qf[4][4];
  #pragma unroll
  for (int a = 0; a < 4; a++)
    #pragma unroll
    for (int s = 0; s < 4; s++)
      Qf[a][s] = Qp8[((size_t)((b * 256 + tq) * 16 + a * 4 + s)) * 64 + l];

  f32x4 O[4], Oe;
  #pragma unroll
  for (int nt = 0; nt < 4; nt++) O[nt] = (f32x4){0.f, 0.f, 0.f, 0.f};
  Oe = (f32x4){0.f, 0.f, 0.f, 0.f};
  float Mq = -3e38f;
  short8 Vreg[2][4];
  const short b1 = (short)0x3F80;
  const short8 ones = {b1, b1, b1, b1, b1, b1, b1, b1};

  const char* Kg = (const char*)Kpk;
  {
    const char* gsrc = Kg + ((size_t)(b * 64) << 16);
    char* lb = (char*)&Klds[0][0];
    #pragma unroll
    for (int i2 = 0; i2 < 8; i2++) {
      int ch = w + 8 * i2;
      gload_lds16(gsrc + ch * 1024 + l * 16, lb + ch * 1024);
    }
  }
  const short8* Vp8 = (const short8*)Vpk;
  f32x4 s0;

  for (int mt = 0; mt < 64; mt++) {
    const int cur = mt & 1;
    __syncthreads();   // SYNC A: Klds[cur] DMA drained; Pfrag(t-1)/escs(t-1) ready
    if (mt + 1 < 64) {
      const char* gsrc = Kg + ((size_t)(b * 64 + mt + 1) << 16);
      char* lb = (char*)&Klds[cur ^ 1][0];
      #pragma unroll
      for (int i2 = 0; i2 < 8; i2++) {
        int ch = w + 8 * i2;
        gload_lds16(gsrc + ch * 1024 + l * 16, lb + ch * 1024);
      }
    }
    // ---- PV(t-1): rescale by esc(t-1), accumulate P(t-1)·V(t-1) ----
    if (mt > 0) {
      f32x4 ev = *(const f32x4*)&escs[qg][4 * g];
      #pragma unroll
      for (int r = 0; r < 4; r++) {
        #pragma unroll
        for (int nt = 0; nt < 4; nt++) O[nt][r] *= ev[r];
        Oe[r] *= ev[r];
      }
      #pragma unroll
      for (int ks = 0; ks < 2; ks++) {
        short8 Pa = *(const short8*)&Pfrag[(qg * 16 + c) * 72 + 32 * ks + 8 * g];
        #pragma unroll
        for (int nt = 0; nt < 4; nt++)
          O[nt] = MFMA16(Pa, Vreg[ks][nt], O[nt]);
        Oe = MFMA16(Pa, ones, Oe);
      }
    }
    // ---- QK^T(t), swapped: D[m,q], split bf16 hh+hl+lh ----
    const short8* kb8 = (const short8*)&Klds[cur][0];
    f32x4 sr = (f32x4){0, 0, 0, 0}, si = (f32x4){0, 0, 0, 0};
    #pragma unroll
    for (int s = 0; s < 4; s++) {
      short8 Arh = kb8[((0 * 4 + ms) * 4 + s) * 64 + l];
      short8 Arl = kb8[((1 * 4 + ms) * 4 + s) * 64 + l];
      short8 Aih = kb8[((2 * 4 + ms) * 4 + s) * 64 + l];
      short8 Ail = kb8[((3 * 4 + ms) * 4 + s) * 64 + l];
      short8 nqh = neg8(Qf[2][s]);
      short8 nql = neg8(Qf[3][s]);
      sr = MFMA16(Arh, Qf[0][s], sr);   // Krh*Qrh
      si = MFMA16(Arh, Qf[2][s], si);   // Krh*Qih
      sr = MFMA16(Arh, Qf[1][s], sr);   // Krh*Qrl
      si = MFMA16(Arh, Qf[3][s], si);   // Krh*Qil
      sr = MFMA16(Arl, Qf[0][s], sr);   // Krl*Qrh
      si = MFMA16(Arl, Qf[2][s], si);   // Krl*Qih
      sr = MFMA16(Aih, nqh, sr);        // -Kih*Qih
      si = MFMA16(Aih, Qf[0][s], si);   // Kih*Qrh
      sr = MFMA16(Aih, nql, sr);        // -Kih*Qil
      si = MFMA16(Aih, Qf[1][s], si);   // Kih*Qrl
      sr = MFMA16(Ail, nqh, sr);        // -Kil*Qih
      si = MFMA16(Ail, Qf[0][s], si);   // Kil*Qrh
    }
    // ---- scores + slice-max (per lane: 4 m for q=c) ----
    float mloc;
    #pragma unroll
    for (int r = 0; r < 4; r++)
      s0[r] = sqrtf(sr[r] * sr[r] + si[r] * si[r] + 1e-8f);
    mloc = fmaxf(fmaxf(s0[0], s0[1]), fmaxf(s0[2], s0[3]));
    mloc = fmaxf(mloc, __shfl_xor(mloc, 16));
    mloc = fmaxf(mloc, __shfl_xor(mloc, 32));
    if (l < 16) rmax[qg][l][ms] = mloc;
    __syncthreads();   // SYNC B: rmax ready; PV(t-1) done with Pfrag
    {
      f32x4 rm4 = *(const f32x4*)&rmax[qg][c][0];
      float nmq = fmaxf(fmaxf(rm4[0], rm4[1]), fmaxf(rm4[2], rm4[3]));
      nmq = fmaxf(Mq, nmq);
      float escq = __expf(Mq - nmq);
      Mq = nmq;
      if (ms == 0 && l < 16) escs[qg][l] = escq;
      // V(t) prefetch into regs (consumed by PV at iter t+1)
      #pragma unroll
      for (int ks = 0; ks < 2; ks++)
        #pragma unroll
        for (int nt = 0; nt < 4; nt++)
          Vreg[ks][nt] = Vp8[((size_t)((b * 128 + mt * 2 + ks) * 16 + ms * 4 + nt)) * 64 + l];
      f32x4 p;
      #pragma unroll
      for (int r = 0; r < 4; r++) p[r] = __expf(s0[r] - nmq);
      unsigned int w01 = (unsigned int)f2bf(p[0]) | ((unsigned int)f2bf(p[1]) << 16);
      unsigned int w23 = (unsigned int)f2bf(p[2]) | ((unsigned int)f2bf(p[3]) << 16);
      unsigned int* pw = (unsigned int*)&Pfrag[(qg * 16 + c) * 72 + 16 * ms + 4 * g];
      pw[0] = w01; pw[1] = w23;
    }
  }
  __syncthreads();
  // ---- tail PV(63) ----
  {
    f32x4 ev = *(const f32x4*)&escs[qg][4 * g];
    #pragma unroll
    for (int r = 0; r < 4; r++) {
      #pragma unroll
      for (int nt = 0; nt < 4; nt++) O[nt][r] *= ev[r];
      Oe[r] *= ev[r];
    }
    #pragma unroll
    for (int ks = 0; ks < 2; ks++) {
      short8 Pa = *(const short8*)&Pfrag[(qg * 16 + c) * 72 + 32 * ks + 8 * g];
      #pragma unroll
      for (int nt = 0; nt < 4; nt++)
        O[nt] = MFMA16(Pa, Vreg[ks][nt], O[nt]);
      Oe = MFMA16(Pa, ones, Oe);
    }
  }
  // ---- normalize + write out (PV-land: row q = 4g+r, col cc = ms*64+nt*16+c)
  const size_t base = (size_t)b * 4096 * 128;
  f32x4 inv;
  #pragma unroll
  for (int r = 0; r < 4; r++) inv[r] = 1.0f / Oe[r];
  #pragma unroll
  for (int nt = 0; nt < 4; nt++) {
    int cc = ms * 64 + nt * 16 + c;
    #pragma unroll
    for (int r = 0; r < 4; r++) {
      int row = qt * 32 + qg * 16 + 4 * g + r;
      float v = O[nt][r] * inv[r];
      if (cc < 128) Or_[base + (size_t)row * 128 + cc] = v;
      else          Oi_[base + (size_t)row * 128 + cc - 128] = v;
    }
  }
}

// ---------------------------------------------------------------------------
// Kernel 4: inverse DFT2 (real part), output [b][c][h][w]
// ---------------------------------------------------------------------------
__global__ __launch_bounds__(256) void idft2_kernel(
    const float* __restrict__ Or_, const float* __restrict__ Oi_,
    float* __restrict__ out)
{
  __shared__ float Ar[4096], Ai[4096], Tr[4096], Ti[4096];
  __shared__ float twc[64], tws[64];
  int plane = blockIdx.x; int b = plane >> 7, c = plane & 127;
  int t = threadIdx.x;
  if (t < 64) {
    float ang = PI2 * (float)t / 64.0f;
    twc[t] = cosf(ang); tws[t] = sinf(ang);
  }
  size_t ibase = (size_t)b * 4096 * 128 + c;
  for (int i = t; i < 4096; i += 256) {
    Ar[i] = Or_[ibase + (size_t)i * 128];
    Ai[i] = Oi_[ibase + (size_t)i * 128];
  }
  __syncthreads();
  for (int j = 0; j < 16; j++) {
    int o = t + 256 * j; int hp = o >> 6, w = o & 63;
    float tr = 0.f, ti = 0.f;
    for (int wp = 0; wp < 64; wp++) {
      int k = (wp * w) & 63;
      float cr = twc[k], ci = tws[k];
      float ar = Ar[hp * 64 + wp], ai = Ai[hp * 64 + wp];
      tr += ar * cr - ai * ci;
      ti += ai * cr + ar * ci;
    }
    Tr[hp * 64 + w] = tr; Ti[hp * 64 + w] = ti;
  }
  __syncthreads();
  size_t obase = ((size_t)plane) << 12;
  for (int j = 0; j < 16; j++) {
    int o = t + 256 * j; int h = o >> 6, w = o & 63;
    float acc = 0.f;
    for (int hp = 0; hp < 64; hp++) {
      int k = (hp * h) & 63;
      acc += Tr[hp * 64 + w] * twc[k] - Ti[hp * 64 + w] * tws[k];
    }
    out[obase + o] = acc * (1.0f / 4096.0f);
  }
}

extern "C" void kernel_launch(void* const* d_in, const int* in_sizes, int n_in,
                              void* d_out, int out_size, void* d_ws, size_t ws_size,
                              hipStream_t stream) {
  const float* x   = (const float*)d_in[0];
  const float* y   = (const float*)d_in[1];
  const float* Wqr = (const float*)d_in[2];  const float* bqr = (const float*)d_in[3];
  const float* Wqi = (const float*)d_in[4];  const float* bqi = (const float*)d_in[5];
  const float* Wkr = (const float*)d_in[6];  const float* bkr = (const float*)d_in[7];
  const float* Wki = (const float*)d_in[8];  const float* bki = (const float*)d_in[9];
  const float* Wvr = (const float*)d_in[10]; const float* bvr = (const float*)d_in[11];
  const float* Wvi = (const float*)d_in[12]; const float* bvi = (const float*)d_in[13];
  char* wsb = (char*)d_ws;
  if (ws_size < ((size_t)36 << 20)) return;  // need 36 MiB
  unsigned short* Qpk = (unsigned short*)(wsb);
  unsigned short* Kpk = (unsigned short*)(wsb + ((size_t)8 << 20));
  unsigned short* Vpk = (unsigned short*)(wsb + ((size_t)16 << 20));
  float* xr = (float*)(wsb + ((size_t)20 << 20));
  float* xi = (float*)(wsb + ((size_t)24 << 20));
  float* yr = (float*)(wsb + ((size_t)28 << 20));
  float* yi = (float*)(wsb + ((size_t)32 << 20));
  float* Or_ = (float*)(wsb + ((size_t)20 << 20));  // overlay xr/xi (dead after proj)
  float* Oi_ = (float*)(wsb + ((size_t)24 << 20));
  float* out = (float*)d_out;

  hipLaunchKernelGGL(dft2_fwd_kernel, dim3(512), dim3(256), 0, stream,
                     x, y, xr, xi, yr, yi);
  hipLaunchKernelGGL(proj_pack_t<0>, dim3(64, 2), dim3(256), 0, stream,
                     xr, xi, Wqr, Wqi, bqr, bqi, Qpk);
  hipLaunchKernelGGL(proj_pack_t<1>, dim3(64, 2), dim3(256), 0, stream,
                     yr, yi, Wkr, Wki, bkr, bki, Kpk);
  hipLaunchKernelGGL(proj_pack_t<2>, dim3(64, 2), dim3(256), 0, stream,
                     yr, yi, Wvr, Wvi, bvr, bvi, Vpk);
  hipLaunchKernelGGL(attn_mfma_kernel, dim3(256), dim3(512), 0, stream,
                     (const short*)Qpk, (const short*)Kpk, (const short*)Vpk, Or_, Oi_);
  hipLaunchKernelGGL(idft2_kernel, dim3(256), dim3(256), 0, stream,
                     Or_, Oi_, out);
}

// Round 5
// 434.748 us; speedup vs baseline: 4.3945x; 1.0636x over previous
//
#include <hip/hip_runtime.h>
#include <math.h>

// B=2, C=128, H=W=64, N=4096.
// ws layout (bytes), total 40 MiB:
//   [0,8M)   FQ: Q bf16 split planes [p:rh,rl,ih,il][b][n][c]   (2 MB/plane)
//   [8,16M)  FK: K bf16 split planes (same)
//   [16,20M) FV: V bf16 planes [p:r,i][b][n][c]
//   [20,36M) spectra xr,xi,yr,yi fp32 (dead after proj)
//   [20,28M) Qpk  frag-packed [b][tq(256)][a(4)][s(4)][l(64)][j(8)]   (overlay)
//   [28,36M) Kpk  frag-packed [b][mt(64)][a(4)][tml(4)][s(4)][l(64)][j(8)]
//   [36,40M) Vpk  frag-packed [b][sm(128)][tc(16)][l(64)][j(8)]
//   [0,8M)   Or_/Oi_ fp32 [b][n][c] (overlay FQ, dead after qpack)
// frag map: lane l holds X[row=l&15][k=32s+8*(l>>4)+j]

#define PI2 6.283185307179586f

typedef __attribute__((ext_vector_type(8))) short short8;
typedef __attribute__((ext_vector_type(4))) float f32x4;

#define MFMA16(A,B,C) __builtin_amdgcn_mfma_f32_16x16x32_bf16((A),(B),(C),0,0,0)

__device__ inline unsigned short f2bf(float x){
  union{float f; unsigned int u;} a; a.f = x;
  unsigned int r = (a.u + 0x7fffu + ((a.u>>16)&1u)) >> 16;
  return (unsigned short)r;
}
__device__ inline float bf2f(unsigned short h){
  union{unsigned int u; float f;} a; a.u = ((unsigned int)h)<<16; return a.f;
}
__device__ inline short8 neg8(short8 x){
  union{short8 v; unsigned int u[4];} a; a.v = x;
  a.u[0]^=0x80008000u; a.u[1]^=0x80008000u; a.u[2]^=0x80008000u; a.u[3]^=0x80008000u;
  return a.v;
}
__device__ inline void gload_lds16(const void* g, void* lds){
  __builtin_amdgcn_global_load_lds((const __attribute__((address_space(1))) unsigned int*)g,
                                   (__attribute__((address_space(3))) unsigned int*)lds,
                                   16, 0, 0);
}

// ---------------------------------------------------------------------------
// Kernel 1: forward DFT2 of x and y (two 64-pt DFT stages per (b,c) plane)
// (unchanged from round 1)
// ---------------------------------------------------------------------------
__global__ __launch_bounds__(256) void dft2_fwd_kernel(
    const float* __restrict__ x, const float* __restrict__ y,
    float* __restrict__ xr, float* __restrict__ xi,
    float* __restrict__ yr, float* __restrict__ yi)
{
  __shared__ float Xs[4096];
  __shared__ float Tr[4096], Ti[4096];
  __shared__ float twc[64], tws[64];
  int blk = blockIdx.x;
  const float* src; float *outr, *outi;
  int plane;
  if (blk < 256) { src = x; outr = xr; outi = xi; plane = blk; }
  else           { src = y; outr = yr; outi = yi; plane = blk - 256; }
  int b = plane >> 7, c = plane & 127;
  int t = threadIdx.x;
  if (t < 64) {
    float ang = -PI2 * (float)t / 64.0f;
    twc[t] = cosf(ang); tws[t] = sinf(ang);
  }
  const float* p = src + ((size_t)plane << 12);
  for (int i = t; i < 4096; i += 256) Xs[i] = p[i];
  __syncthreads();
  for (int j = 0; j < 16; j++) {
    int o = t + 256 * j; int h = o >> 6, wp = o & 63;
    float ar = 0.f, ai = 0.f;
    for (int w = 0; w < 64; w++) {
      int k = (w * wp) & 63;
      float v = Xs[h * 64 + w];
      ar = fmaf(v, twc[k], ar);
      ai = fmaf(v, tws[k], ai);
    }
    Tr[h * 64 + wp] = ar; Ti[h * 64 + wp] = ai;
  }
  __syncthreads();
  size_t ob = ((size_t)b * 4096) * 128 + c;
  for (int j = 0; j < 16; j++) {
    int o = t + 256 * j; int hp = o >> 6, wp = o & 63;
    float ar = 0.f, ai = 0.f;
    for (int h = 0; h < 64; h++) {
      int k = (h * hp) & 63;
      float cr = twc[k], ci = tws[k];
      float tr = Tr[h * 64 + wp], ti = Ti[h * 64 + wp];
      ar += tr * cr - ti * ci;
      ai += tr * ci + ti * cr;
    }
    int n = (hp << 6) + wp;
    outr[ob + (size_t)n * 128] = ar;
    outi[ob + (size_t)n * 128] = ai;
  }
}

// ---------------------------------------------------------------------------
// Kernel 2: complex projections (round-1-proven structure). Epilogue writes
// plane-major bf16 hi/lo split flats [p][b][n][c] — simple coalesced stores.
// grid (64 n-tiles, 3 lin, 2 b)
// ---------------------------------------------------------------------------
__global__ __launch_bounds__(256) void proj_kernel(
    const float* __restrict__ xr, const float* __restrict__ xi,
    const float* __restrict__ yr, const float* __restrict__ yi,
    const float* __restrict__ Wqr, const float* __restrict__ bqr,
    const float* __restrict__ Wqi, const float* __restrict__ bqi,
    const float* __restrict__ Wkr, const float* __restrict__ bkr,
    const float* __restrict__ Wki, const float* __restrict__ bki,
    const float* __restrict__ Wvr, const float* __restrict__ bvr,
    const float* __restrict__ Wvi, const float* __restrict__ bvi,
    unsigned short* __restrict__ FQ, unsigned short* __restrict__ FK,
    unsigned short* __restrict__ FV)
{
  __shared__ float Asr[64 * 33], Asi[64 * 33], Wsr[128 * 33], Wsi[128 * 33];
  int nt = blockIdx.x, lin = blockIdx.y, b = blockIdx.z;
  const float *ar, *ai, *Wr, *Wi, *br_, *bi_;
  unsigned short* F;
  if (lin == 0)      { ar = xr; ai = xi; Wr = Wqr; Wi = Wqi; br_ = bqr; bi_ = bqi; F = FQ; }
  else if (lin == 1) { ar = yr; ai = yi; Wr = Wkr; Wi = Wki; br_ = bkr; bi_ = bki; F = FK; }
  else               { ar = yr; ai = yi; Wr = Wvr; Wi = Wvi; br_ = bvr; bi_ = bvi; F = FV; }
  int t = threadIdx.x; int td = t & 15, tn = t >> 4;
  int n0 = nt * 64;
  size_t abase = (size_t)b * 4096 * 128 + (size_t)n0 * 128;
  const size_t PS = (size_t)2 * 4096 * 128;   // plane stride (ushorts)
  float accr[4][8] = {}, acci[4][8] = {};
  for (int kk = 0; kk < 4; kk++) {
    __syncthreads();
    for (int idx = t; idx < 64 * 32; idx += 256) {
      int r = idx >> 5, ccol = idx & 31;
      Asr[r * 33 + ccol] = ar[abase + (size_t)r * 128 + kk * 32 + ccol];
      Asi[r * 33 + ccol] = ai[abase + (size_t)r * 128 + kk * 32 + ccol];
    }
    for (int idx = t; idx < 128 * 32; idx += 256) {
      int r = idx >> 5, ccol = idx & 31;
      Wsr[r * 33 + ccol] = Wr[(size_t)r * 128 + kk * 32 + ccol];
      Wsi[r * 33 + ccol] = Wi[(size_t)r * 128 + kk * 32 + ccol];
    }
    __syncthreads();
    for (int k = 0; k < 32; k++) {
      float a_r[4], a_i[4], w_r[8], w_i[8];
      #pragma unroll
      for (int i = 0; i < 4; i++) {
        a_r[i] = Asr[(tn * 4 + i) * 33 + k];
        a_i[i] = Asi[(tn * 4 + i) * 33 + k];
      }
      #pragma unroll
      for (int jj = 0; jj < 8; jj++) {
        w_r[jj] = Wsr[(td + 16 * jj) * 33 + k];
        w_i[jj] = Wsi[(td + 16 * jj) * 33 + k];
      }
      #pragma unroll
      for (int i = 0; i < 4; i++)
        #pragma unroll
        for (int jj = 0; jj < 8; jj++) {
          accr[i][jj] += a_r[i] * w_r[jj] - a_i[i] * w_i[jj];
          acci[i][jj] += a_i[i] * w_r[jj] + a_r[i] * w_i[jj];
        }
    }
  }
  for (int jj = 0; jj < 8; jj++) {
    int d = td + 16 * jj;
    float brd = br_[d], bid = bi_[d];
    #pragma unroll
    for (int i = 0; i < 4; i++) {
      int n = n0 + tn * 4 + i;
      float cr = accr[i][jj] + (brd - bid);
      float ci = acci[i][jj] + (brd + bid);
      size_t base = ((size_t)b * 4096 + n) * 128 + d;
      if (lin <= 1) {
        unsigned short rh = f2bf(cr); unsigned short rl = f2bf(cr - bf2f(rh));
        unsigned short ih = f2bf(ci); unsigned short il = f2bf(ci - bf2f(ih));
        F[0 * PS + base] = rh;
        F[1 * PS + base] = rl;
        F[2 * PS + base] = ih;
        F[3 * PS + base] = il;
      } else {
        F[0 * PS + base] = f2bf(cr);
        F[1 * PS + base] = f2bf(ci);
      }
    }
  }
}

// ---------------------------------------------------------------------------
// Kernel 2b/2c/2d: pure-permutation pack kernels (short8 copy, write-coalesced)
// ---------------------------------------------------------------------------
__global__ __launch_bounds__(256) void qpack_kernel(
    const unsigned short* __restrict__ F, unsigned short* __restrict__ Qpk)
{
  int blk = blockIdx.x;                 // b*256 + tq
  int b = blk >> 8, tq = blk & 255;
  int t = threadIdx.x;
  #pragma unroll
  for (int k = 0; k < 4; k++) {
    int idx = t + 256 * k;              // [0,1024): a(2)|s(2)|l(6)
    int l = idx & 63, s = (idx >> 6) & 3, a = idx >> 8;
    int n = tq * 16 + (l & 15);
    int c0 = 32 * s + 8 * (l >> 4);
    const short8 v = *(const short8*)(F + (((size_t)(a * 2 + b) * 4096 + n) * 128 + c0));
    *(short8*)(Qpk + (((size_t)((b * 256 + tq) * 16 + a * 4 + s)) * 64 + l) * 8) = v;
  }
}

__global__ __launch_bounds__(256) void kpack_kernel(
    const unsigned short* __restrict__ F, unsigned short* __restrict__ Kpk)
{
  int blk = blockIdx.x;                 // b*64 + mt
  int b = blk >> 6, mt = blk & 63;
  int t = threadIdx.x;
  size_t obase = (size_t)blk * 4096;    // short8 units per tile
  #pragma unroll
  for (int k = 0; k < 16; k++) {
    int idx = t + 256 * k;              // [0,4096): a(2)|tml(2)|s(2)|l(6)
    int l = idx & 63, s = (idx >> 6) & 3, tml = (idx >> 8) & 3, a = idx >> 10;
    int n = mt * 64 + tml * 16 + (l & 15);
    int c0 = 32 * s + 8 * (l >> 4);
    const short8 v = *(const short8*)(F + (((size_t)(a * 2 + b) * 4096 + n) * 128 + c0));
    *(short8*)(Kpk + (obase + idx) * 8) = v;
  }
}

__global__ __launch_bounds__(256) void vpack_kernel(
    const unsigned short* __restrict__ F, unsigned short* __restrict__ Vpk)
{
  __shared__ unsigned short Vs[2 * 32 * 128];   // [p][nn][d]
  int blk = blockIdx.x;                 // b*128 + sm
  int b = blk >> 7, sm = blk & 127;
  int t = threadIdx.x;
  const size_t PS = (size_t)2 * 4096 * 128;
  // load 32 rows x 128 d x 2 planes, coalesced
  #pragma unroll
  for (int p = 0; p < 2; p++) {
    #pragma unroll
    for (int k = 0; k < 2; k++) {
      int idx8 = t + 256 * k;           // [0,512): nn(5)|d8(4)
      int nn = idx8 >> 4, d0 = (idx8 & 15) * 8;
      const short8 v = *(const short8*)(F + p * PS + ((size_t)(b * 4096 + sm * 32 + nn)) * 128 + d0);
      *(short8*)(Vs + (p * 32 + nn) * 128 + d0) = v;
    }
  }
  __syncthreads();
  size_t obase = (size_t)blk * 1024;    // short8 units per tile
  #pragma unroll
  for (int k = 0; k < 4; k++) {
    int idx = t + 256 * k;              // [0,1024): tc(4)|lv(6)
    int lv = idx & 63, tc = idx >> 6;
    int vh = tc >> 3;
    int d = (tc & 7) * 16 + (lv & 15);
    int nb = (lv >> 4) * 8;
    short8 v;
    #pragma unroll
    for (int j = 0; j < 8; j++)
      v[j] = (short)Vs[(vh * 32 + nb + j) * 128 + d];
    *(short8*)(Vpk + (obase + idx) * 8) = v;
  }
}

// ---------------------------------------------------------------------------
// Kernel 3: MFMA flash attention (unchanged from round 4).
// swapped QK^T (A=K from LDS, B=Q regs), pipelined PV, L via ones-col MFMA.
// ---------------------------------------------------------------------------
__global__ __launch_bounds__(512, 1) void attn_mfma_kernel(
    const short* __restrict__ Qpk, const short* __restrict__ Kpk,
    const short* __restrict__ Vpk,
    float* __restrict__ Or_, float* __restrict__ Oi_)
{
  __shared__ __align__(16) short Klds[2][32768];
  __shared__ __align__(16) short Pfrag[2 * 16 * 72];   // [qg][q][64m + 8 pad]
  __shared__ __align__(16) float rmax[2][16][4];       // [qg][q][ms]
  __shared__ __align__(16) float escs[2][16];          // [qg][q]

  const int bi = blockIdx.x;
  const int xg = bi & 7;
  const int b = xg >> 2;                      // XCDs 0-3 -> b=0, 4-7 -> b=1
  const int qt = (bi >> 3) * 4 + (xg & 3);
  const int t = threadIdx.x;
  const int w = t >> 6, l = t & 63;
  const int qg = w & 1, ms = w >> 1;
  const int g = l >> 4, c = l & 15;

  const short8* Qp8 = (const short8*)Qpk;
  const int tq = qt * 2 + qg;
  short8 Qf[4][4];
  #pragma unroll
  for (int a = 0; a < 4; a++)
    #pragma unroll
    for (int s = 0; s < 4; s++)
      Qf[a][s] = Qp8[((size_t)((b * 256 + tq) * 16 + a * 4 + s)) * 64 + l];

  f32x4 O[4], Oe;
  #pragma unroll
  for (int nt = 0; nt < 4; nt++) O[nt] = (f32x4){0.f, 0.f, 0.f, 0.f};
  Oe = (f32x4){0.f, 0.f, 0.f, 0.f};
  float Mq = -3e38f;
  short8 Vreg[2][4];
  const short b1 = (short)0x3F80;
  const short8 ones = {b1, b1, b1, b1, b1, b1, b1, b1};

  const char* Kg = (const char*)Kpk;
  {
    const char* gsrc = Kg + ((size_t)(b * 64) << 16);
    char* lb = (char*)&Klds[0][0];
    #pragma unroll
    for (int i2 = 0; i2 < 8; i2++) {
      int ch = w + 8 * i2;
      gload_lds16(gsrc + ch * 1024 + l * 16, lb + ch * 1024);
    }
  }
  const short8* Vp8 = (const short8*)Vpk;
  f32x4 s0;

  for (int mt = 0; mt < 64; mt++) {
    const int cur = mt & 1;
    __syncthreads();   // SYNC A: Klds[cur] DMA drained; Pfrag(t-1)/escs(t-1) ready
    if (mt + 1 < 64) {
      const char* gsrc = Kg + ((size_t)(b * 64 + mt + 1) << 16);
      char* lb = (char*)&Klds[cur ^ 1][0];
      #pragma unroll
      for (int i2 = 0; i2 < 8; i2++) {
        int ch = w + 8 * i2;
        gload_lds16(gsrc + ch * 1024 + l * 16, lb + ch * 1024);
      }
    }
    // ---- PV(t-1) ----
    if (mt > 0) {
      f32x4 ev = *(const f32x4*)&escs[qg][4 * g];
      #pragma unroll
      for (int r = 0; r < 4; r++) {
        #pragma unroll
        for (int nt = 0; nt < 4; nt++) O[nt][r] *= ev[r];
        Oe[r] *= ev[r];
      }
      #pragma unroll
      for (int ks = 0; ks < 2; ks++) {
        short8 Pa = *(const short8*)&Pfrag[(qg * 16 + c) * 72 + 32 * ks + 8 * g];
        #pragma unroll
        for (int nt = 0; nt < 4; nt++)
          O[nt] = MFMA16(Pa, Vreg[ks][nt], O[nt]);
        Oe = MFMA16(Pa, ones, Oe);
      }
    }
    // ---- QK^T(t), swapped, split bf16 hh+hl+lh ----
    const short8* kb8 = (const short8*)&Klds[cur][0];
    f32x4 sr = (f32x4){0, 0, 0, 0}, si = (f32x4){0, 0, 0, 0};
    #pragma unroll
    for (int s = 0; s < 4; s++) {
      short8 Arh = kb8[((0 * 4 + ms) * 4 + s) * 64 + l];
      short8 Arl = kb8[((1 * 4 + ms) * 4 + s) * 64 + l];
      short8 Aih = kb8[((2 * 4 + ms) * 4 + s) * 64 + l];
      short8 Ail = kb8[((3 * 4 + ms) * 4 + s) * 64 + l];
      short8 nqh = neg8(Qf[2][s]);
      short8 nql = neg8(Qf[3][s]);
      sr = MFMA16(Arh, Qf[0][s], sr);
      si = MFMA16(Arh, Qf[2][s], si);
      sr = MFMA16(Arh, Qf[1][s], sr);
      si = MFMA16(Arh, Qf[3][s], si);
      sr = MFMA16(Arl, Qf[0][s], sr);
      si = MFMA16(Arl, Qf[2][s], si);
      sr = MFMA16(Aih, nqh, sr);
      si = MFMA16(Aih, Qf[0][s], si);
      sr = MFMA16(Aih, nql, sr);
      si = MFMA16(Aih, Qf[1][s], si);
      sr = MFMA16(Ail, nqh, sr);
      si = MFMA16(Ail, Qf[0][s], si);
    }
    // ---- scores + slice-max ----
    float mloc;
    #pragma unroll
    for (int r = 0; r < 4; r++)
      s0[r] = sqrtf(sr[r] * sr[r] + si[r] * si[r] + 1e-8f);
    mloc = fmaxf(fmaxf(s0[0], s0[1]), fmaxf(s0[2], s0[3]));
    mloc = fmaxf(mloc, __shfl_xor(mloc, 16));
    mloc = fmaxf(mloc, __shfl_xor(mloc, 32));
    if (l < 16) rmax[qg][l][ms] = mloc;
    __syncthreads();   // SYNC B: rmax ready; PV(t-1) done with Pfrag
    {
      f32x4 rm4 = *(const f32x4*)&rmax[qg][c][0];
      float nmq = fmaxf(fmaxf(rm4[0], rm4[1]), fmaxf(rm4[2], rm4[3]));
      nmq = fmaxf(Mq, nmq);
      float escq = __expf(Mq - nmq);
      Mq = nmq;
      if (ms == 0 && l < 16) escs[qg][l] = escq;
      #pragma unroll
      for (int ks = 0; ks < 2; ks++)
        #pragma unroll
        for (int nt = 0; nt < 4; nt++)
          Vreg[ks][nt] = Vp8[((size_t)((b * 128 + mt * 2 + ks) * 16 + ms * 4 + nt)) * 64 + l];
      f32x4 p;
      #pragma unroll
      for (int r = 0; r < 4; r++) p[r] = __expf(s0[r] - nmq);
      unsigned int w01 = (unsigned int)f2bf(p[0]) | ((unsigned int)f2bf(p[1]) << 16);
      unsigned int w23 = (unsigned int)f2bf(p[2]) | ((unsigned int)f2bf(p[3]) << 16);
      unsigned int* pw = (unsigned int*)&Pfrag[(qg * 16 + c) * 72 + 16 * ms + 4 * g];
      pw[0] = w01; pw[1] = w23;
    }
  }
  __syncthreads();
  // ---- tail PV(63) ----
  {
    f32x4 ev = *(const f32x4*)&escs[qg][4 * g];
    #pragma unroll
    for (int r = 0; r < 4; r++) {
      #pragma unroll
      for (int nt = 0; nt < 4; nt++) O[nt][r] *= ev[r];
      Oe[r] *= ev[r];
    }
    #pragma unroll
    for (int ks = 0; ks < 2; ks++) {
      short8 Pa = *(const short8*)&Pfrag[(qg * 16 + c) * 72 + 32 * ks + 8 * g];
      #pragma unroll
      for (int nt = 0; nt < 4; nt++)
        O[nt] = MFMA16(Pa, Vreg[ks][nt], O[nt]);
      Oe = MFMA16(Pa, ones, Oe);
    }
  }
  // ---- normalize + write out ----
  const size_t base = (size_t)b * 4096 * 128;
  f32x4 inv;
  #pragma unroll
  for (int r = 0; r < 4; r++) inv[r] = 1.0f / Oe[r];
  #pragma unroll
  for (int nt = 0; nt < 4; nt++) {
    int cc = ms * 64 + nt * 16 + c;
    #pragma unroll
    for (int r = 0; r < 4; r++) {
      int row = qt * 32 + qg * 16 + 4 * g + r;
      float v = O[nt][r] * inv[r];
      if (cc < 128) Or_[base + (size_t)row * 128 + cc] = v;
      else          Oi_[base + (size_t)row * 128 + cc - 128] = v;
    }
  }
}

// ---------------------------------------------------------------------------
// Kernel 4: inverse DFT2 (real part), output [b][c][h][w]  (unchanged)
// ---------------------------------------------------------------------------
__global__ __launch_bounds__(256) void idft2_kernel(
    const float* __restrict__ Or_, const float* __restrict__ Oi_,
    float* __restrict__ out)
{
  __shared__ float Ar[4096], Ai[4096], Tr[4096], Ti[4096];
  __shared__ float twc[64], tws[64];
  int plane = blockIdx.x; int b = plane >> 7, c = plane & 127;
  int t = threadIdx.x;
  if (t < 64) {
    float ang = PI2 * (float)t / 64.0f;
    twc[t] = cosf(ang); tws[t] = sinf(ang);
  }
  size_t ibase = (size_t)b * 4096 * 128 + c;
  for (int i = t; i < 4096; i += 256) {
    Ar[i] = Or_[ibase + (size_t)i * 128];
    Ai[i] = Oi_[ibase + (size_t)i * 128];
  }
  __syncthreads();
  for (int j = 0; j < 16; j++) {
    int o = t + 256 * j; int hp = o >> 6, w = o & 63;
    float tr = 0.f, ti = 0.f;
    for (int wp = 0; wp < 64; wp++) {
      int k = (wp * w) & 63;
      float cr = twc[k], ci = tws[k];
      float ar = Ar[hp * 64 + wp], ai = Ai[hp * 64 + wp];
      tr += ar * cr - ai * ci;
      ti += ai * cr + ar * ci;
    }
    Tr[hp * 64 + w] = tr; Ti[hp * 64 + w] = ti;
  }
  __syncthreads();
  size_t obase = ((size_t)plane) << 12;
  for (int j = 0; j < 16; j++) {
    int o = t + 256 * j; int h = o >> 6, w = o & 63;
    float acc = 0.f;
    for (int hp = 0; hp < 64; hp++) {
      int k = (hp * h) & 63;
      acc += Tr[hp * 64 + w] * twc[k] - Ti[hp * 64 + w] * tws[k];
    }
    out[obase + o] = acc * (1.0f / 4096.0f);
  }
}

extern "C" void kernel_launch(void* const* d_in, const int* in_sizes, int n_in,
                              void* d_out, int out_size, void* d_ws, size_t ws_size,
                              hipStream_t stream) {
  const float* x   = (const float*)d_in[0];
  const float* y   = (const float*)d_in[1];
  const float* Wqr = (const float*)d_in[2];  const float* bqr = (const float*)d_in[3];
  const float* Wqi = (const float*)d_in[4];  const float* bqi = (const float*)d_in[5];
  const float* Wkr = (const float*)d_in[6];  const float* bkr = (const float*)d_in[7];
  const float* Wki = (const float*)d_in[8];  const float* bki = (const float*)d_in[9];
  const float* Wvr = (const float*)d_in[10]; const float* bvr = (const float*)d_in[11];
  const float* Wvi = (const float*)d_in[12]; const float* bvi = (const float*)d_in[13];
  char* wsb = (char*)d_ws;
  if (ws_size < ((size_t)40 << 20)) return;  // need 40 MiB (proven available)
  unsigned short* FQ  = (unsigned short*)(wsb);                      // [0,8M)
  unsigned short* FK  = (unsigned short*)(wsb + ((size_t)8  << 20)); // [8,16M)
  unsigned short* FV  = (unsigned short*)(wsb + ((size_t)16 << 20)); // [16,20M)
  float* xr = (float*)(wsb + ((size_t)20 << 20));
  float* xi = (float*)(wsb + ((size_t)24 << 20));
  float* yr = (float*)(wsb + ((size_t)28 << 20));
  float* yi = (float*)(wsb + ((size_t)32 << 20));
  unsigned short* Qpk = (unsigned short*)(wsb + ((size_t)20 << 20)); // overlay dead spectra
  unsigned short* Kpk = (unsigned short*)(wsb + ((size_t)28 << 20));
  unsigned short* Vpk = (unsigned short*)(wsb + ((size_t)36 << 20));
  float* Or_ = (float*)(wsb);                                        // overlay dead FQ
  float* Oi_ = (float*)(wsb + ((size_t)4 << 20));
  float* out = (float*)d_out;

  hipLaunchKernelGGL(dft2_fwd_kernel, dim3(512), dim3(256), 0, stream,
                     x, y, xr, xi, yr, yi);
  hipLaunchKernelGGL(proj_kernel, dim3(64, 3, 2), dim3(256), 0, stream,
                     xr, xi, yr, yi,
                     Wqr, bqr, Wqi, bqi, Wkr, bkr, Wki, bki, Wvr, bvr, Wvi, bvi,
                     FQ, FK, FV);
  hipLaunchKernelGGL(qpack_kernel, dim3(512), dim3(256), 0, stream, FQ, Qpk);
  hipLaunchKernelGGL(kpack_kernel, dim3(128), dim3(256), 0, stream, FK, Kpk);
  hipLaunchKernelGGL(vpack_kernel, dim3(256), dim3(256), 0, stream, FV, Vpk);
  hipLaunchKernelGGL(attn_mfma_kernel, dim3(256), dim3(512), 0, stream,
                     (const short*)Qpk, (const short*)Kpk, (const short*)Vpk, Or_, Oi_);
  hipLaunchKernelGGL(idft2_kernel, dim3(256), dim3(256), 0, stream,
                     Or_, Oi_, out);
}

// Round 7
// 430.968 us; speedup vs baseline: 4.4330x; 1.0088x over previous
//
#include <hip/hip_runtime.h>
#include <math.h>

// B=2, C=128, H=W=64, N=4096.
// ws layout (bytes), total 40 MiB:
//   [0,8M)   FQ: Q bf16 split planes [p:rh,rl,ih,il][b][n][c]   (2 MB/plane)
//   [8,16M)  FK: K bf16 split planes (same)
//   [16,20M) FV: V bf16 planes [p:r,i][b][n][c]
//   [20,36M) spectra xr,xi,yr,yi fp32 (dead after proj)
//   [36,40M) Vpk frag-packed [b][sm(128)][tc(16)][l(64)][j(8)]
//   [20,28M) Or_/Oi_ fp32 [b][n][c] (overlay dead xr/xi)
// frag map: lane l holds X[row=l&15][k=32s+8*(l>>4)+j]
// K LDS tile: [a(4)][r(64)][u_phys(16)] 16B units, u_phys = u_log ^ (r&7)

#define PI2 6.283185307179586f

typedef __attribute__((ext_vector_type(8))) short short8;
typedef __attribute__((ext_vector_type(4))) float f32x4;

#define MFMA16(A,B,C) __builtin_amdgcn_mfma_f32_16x16x32_bf16((A),(B),(C),0,0,0)

__device__ inline unsigned short f2bf(float x){
  union{float f; unsigned int u;} a; a.f = x;
  unsigned int r = (a.u + 0x7fffu + ((a.u>>16)&1u)) >> 16;
  return (unsigned short)r;
}
__device__ inline float bf2f(unsigned short h){
  union{unsigned int u; float f;} a; a.u = ((unsigned int)h)<<16; return a.f;
}
__device__ inline short8 neg8(short8 x){
  union{short8 v; unsigned int u[4];} a; a.v = x;
  a.u[0]^=0x80008000u; a.u[1]^=0x80008000u; a.u[2]^=0x80008000u; a.u[3]^=0x80008000u;
  return a.v;
}
__device__ inline void gload_lds16(const void* g, void* lds){
  __builtin_amdgcn_global_load_lds((const __attribute__((address_space(1))) unsigned int*)g,
                                   (__attribute__((address_space(3))) unsigned int*)lds,
                                   16, 0, 0);
}

// ---------------------------------------------------------------------------
// Kernel 1: forward DFT2 of x and y (two 64-pt DFT stages per (b,c) plane)
// ---------------------------------------------------------------------------
__global__ __launch_bounds__(256) void dft2_fwd_kernel(
    const float* __restrict__ x, const float* __restrict__ y,
    float* __restrict__ xr, float* __restrict__ xi,
    float* __restrict__ yr, float* __restrict__ yi)
{
  __shared__ float Xs[4096];
  __shared__ float Tr[4096], Ti[4096];
  __shared__ float twc[64], tws[64];
  int blk = blockIdx.x;
  const float* src; float *outr, *outi;
  int plane;
  if (blk < 256) { src = x; outr = xr; outi = xi; plane = blk; }
  else           { src = y; outr = yr; outi = yi; plane = blk - 256; }
  int b = plane >> 7, c = plane & 127;
  int t = threadIdx.x;
  if (t < 64) {
    float ang = -PI2 * (float)t / 64.0f;
    twc[t] = cosf(ang); tws[t] = sinf(ang);
  }
  const float* p = src + ((size_t)plane << 12);
  for (int i = t; i < 4096; i += 256) Xs[i] = p[i];
  __syncthreads();
  for (int j = 0; j < 16; j++) {
    int o = t + 256 * j; int h = o >> 6, wp = o & 63;
    float ar = 0.f, ai = 0.f;
    for (int w = 0; w < 64; w++) {
      int k = (w * wp) & 63;
      float v = Xs[h * 64 + w];
      ar = fmaf(v, twc[k], ar);
      ai = fmaf(v, tws[k], ai);
    }
    Tr[h * 64 + wp] = ar; Ti[h * 64 + wp] = ai;
  }
  __syncthreads();
  size_t ob = ((size_t)b * 4096) * 128 + c;
  for (int j = 0; j < 16; j++) {
    int o = t + 256 * j; int hp = o >> 6, wp = o & 63;
    float ar = 0.f, ai = 0.f;
    for (int h = 0; h < 64; h++) {
      int k = (h * hp) & 63;
      float cr = twc[k], ci = tws[k];
      float tr = Tr[h * 64 + wp], ti = Ti[h * 64 + wp];
      ar += tr * cr - ti * ci;
      ai += tr * ci + ti * cr;
    }
    int n = (hp << 6) + wp;
    outr[ob + (size_t)n * 128] = ar;
    outi[ob + (size_t)n * 128] = ai;
  }
}

// ---------------------------------------------------------------------------
// Kernel 2: complex projections -> flat bf16 split planes (coalesced stores)
// ---------------------------------------------------------------------------
__global__ __launch_bounds__(256) void proj_kernel(
    const float* __restrict__ xr, const float* __restrict__ xi,
    const float* __restrict__ yr, const float* __restrict__ yi,
    const float* __restrict__ Wqr, const float* __restrict__ bqr,
    const float* __restrict__ Wqi, const float* __restrict__ bqi,
    const float* __restrict__ Wkr, const float* __restrict__ bkr,
    const float* __restrict__ Wki, const float* __restrict__ bki,
    const float* __restrict__ Wvr, const float* __restrict__ bvr,
    const float* __restrict__ Wvi, const float* __restrict__ bvi,
    unsigned short* __restrict__ FQ, unsigned short* __restrict__ FK,
    unsigned short* __restrict__ FV)
{
  __shared__ float Asr[64 * 33], Asi[64 * 33], Wsr[128 * 33], Wsi[128 * 33];
  int nt = blockIdx.x, lin = blockIdx.y, b = blockIdx.z;
  const float *ar, *ai, *Wr, *Wi, *br_, *bi_;
  unsigned short* F;
  if (lin == 0)      { ar = xr; ai = xi; Wr = Wqr; Wi = Wqi; br_ = bqr; bi_ = bqi; F = FQ; }
  else if (lin == 1) { ar = yr; ai = yi; Wr = Wkr; Wi = Wki; br_ = bkr; bi_ = bki; F = FK; }
  else               { ar = yr; ai = yi; Wr = Wvr; Wi = Wvi; br_ = bvr; bi_ = bvi; F = FV; }
  int t = threadIdx.x; int td = t & 15, tn = t >> 4;
  int n0 = nt * 64;
  size_t abase = (size_t)b * 4096 * 128 + (size_t)n0 * 128;
  const size_t PS = (size_t)2 * 4096 * 128;
  float accr[4][8] = {}, acci[4][8] = {};
  for (int kk = 0; kk < 4; kk++) {
    __syncthreads();
    for (int idx = t; idx < 64 * 32; idx += 256) {
      int r = idx >> 5, ccol = idx & 31;
      Asr[r * 33 + ccol] = ar[abase + (size_t)r * 128 + kk * 32 + ccol];
      Asi[r * 33 + ccol] = ai[abase + (size_t)r * 128 + kk * 32 + ccol];
    }
    for (int idx = t; idx < 128 * 32; idx += 256) {
      int r = idx >> 5, ccol = idx & 31;
      Wsr[r * 33 + ccol] = Wr[(size_t)r * 128 + kk * 32 + ccol];
      Wsi[r * 33 + ccol] = Wi[(size_t)r * 128 + kk * 32 + ccol];
    }
    __syncthreads();
    for (int k = 0; k < 32; k++) {
      float a_r[4], a_i[4], w_r[8], w_i[8];
      #pragma unroll
      for (int i = 0; i < 4; i++) {
        a_r[i] = Asr[(tn * 4 + i) * 33 + k];
        a_i[i] = Asi[(tn * 4 + i) * 33 + k];
      }
      #pragma unroll
      for (int jj = 0; jj < 8; jj++) {
        w_r[jj] = Wsr[(td + 16 * jj) * 33 + k];
        w_i[jj] = Wsi[(td + 16 * jj) * 33 + k];
      }
      #pragma unroll
      for (int i = 0; i < 4; i++)
        #pragma unroll
        for (int jj = 0; jj < 8; jj++) {
          accr[i][jj] += a_r[i] * w_r[jj] - a_i[i] * w_i[jj];
          acci[i][jj] += a_i[i] * w_r[jj] + a_r[i] * w_i[jj];
        }
    }
  }
  for (int jj = 0; jj < 8; jj++) {
    int d = td + 16 * jj;
    float brd = br_[d], bid = bi_[d];
    #pragma unroll
    for (int i = 0; i < 4; i++) {
      int n = n0 + tn * 4 + i;
      float cr = accr[i][jj] + (brd - bid);
      float ci = acci[i][jj] + (brd + bid);
      size_t base = ((size_t)b * 4096 + n) * 128 + d;
      if (lin <= 1) {
        unsigned short rh = f2bf(cr); unsigned short rl = f2bf(cr - bf2f(rh));
        unsigned short ih = f2bf(ci); unsigned short il = f2bf(ci - bf2f(ih));
        F[0 * PS + base] = rh;
        F[1 * PS + base] = rl;
        F[2 * PS + base] = ih;
        F[3 * PS + base] = il;
      } else {
        F[0 * PS + base] = f2bf(cr);
        F[1 * PS + base] = f2bf(ci);
      }
    }
  }
}

// ---------------------------------------------------------------------------
// Kernel 2b: V pack (transpose to B-frag layout via LDS bounce)
// ---------------------------------------------------------------------------
__global__ __launch_bounds__(256) void vpack_kernel(
    const unsigned short* __restrict__ F, unsigned short* __restrict__ Vpk)
{
  __shared__ unsigned short Vs[2 * 32 * 128];
  int blk = blockIdx.x;
  int b = blk >> 7, sm = blk & 127;
  int t = threadIdx.x;
  const size_t PS = (size_t)2 * 4096 * 128;
  #pragma unroll
  for (int p = 0; p < 2; p++) {
    #pragma unroll
    for (int k = 0; k < 2; k++) {
      int idx8 = t + 256 * k;
      int nn = idx8 >> 4, d0 = (idx8 & 15) * 8;
      const short8 v = *(const short8*)(F + p * PS + ((size_t)(b * 4096 + sm * 32 + nn)) * 128 + d0);
      *(short8*)(Vs + (p * 32 + nn) * 128 + d0) = v;
    }
  }
  __syncthreads();
  size_t obase = (size_t)blk * 1024;
  #pragma unroll
  for (int k = 0; k < 4; k++) {
    int idx = t + 256 * k;
    int lv = idx & 63, tc = idx >> 6;
    int vh = tc >> 3;
    int d = (tc & 7) * 16 + (lv & 15);
    int nb = (lv >> 4) * 8;
    short8 v;
    #pragma unroll
    for (int j = 0; j < 8; j++)
      v[j] = (short)Vs[(vh * 32 + nb + j) * 128 + d];
    *(short8*)(Vpk + (obase + idx) * 8) = v;
  }
}

// ---------------------------------------------------------------------------
// Kernel 3: MFMA flash attention. Counted-vmcnt pipeline (T3/T4), two
// separate K LDS buffers (no aliasing), source-swizzled global_load_lds,
// swapped QK^T, pipelined PV, L via ones-col MFMA, setprio on MFMA cluster.
// ---------------------------------------------------------------------------
__global__ __launch_bounds__(512, 1) void attn_mfma_kernel(
    const unsigned short* __restrict__ FQ, const unsigned short* __restrict__ FK,
    const short* __restrict__ Vpk,
    float* __restrict__ Or_, float* __restrict__ Oi_)
{
  __shared__ __align__(16) short K0lds[32768];
  __shared__ __align__(16) short K1lds[32768];
  __shared__ __align__(16) short Pfrag[2 * 16 * 72];
  __shared__ __align__(16) float rmax[2][16][4];
  __shared__ __align__(16) float escs[2][16];

  const int bi = blockIdx.x;
  const int xg = bi & 7;
  const int b = xg >> 2;                      // XCDs 0-3 -> b=0, 4-7 -> b=1
  const int qt = (bi >> 3) * 4 + (xg & 3);
  const int t = threadIdx.x;
  const int w = t >> 6, l = t & 63;
  const int qg = w & 1, ms = w >> 1;
  const int g = l >> 4, c = l & 15;

  // Q frags straight from flat planes: 16 x 16B loads, once per block
  const int tq = qt * 2 + qg;
  short8 Qf[4][4];
  #pragma unroll
  for (int a = 0; a < 4; a++)
    #pragma unroll
    for (int s = 0; s < 4; s++)
      Qf[a][s] = *(const short8*)(FQ + (((size_t)((a * 2 + b) * 4096) + tq * 16 + c) * 128 + 32 * s + 8 * g));

  f32x4 O[4], Oe;
  #pragma unroll
  for (int nt = 0; nt < 4; nt++) O[nt] = (f32x4){0.f, 0.f, 0.f, 0.f};
  Oe = (f32x4){0.f, 0.f, 0.f, 0.f};
  float Mq = -3e38f;
  short8 Vreg[2][4];
  const short b1 = (short)0x3F80;
  const short8 ones = {b1, b1, b1, b1, b1, b1, b1, b1};
  const short8* Vp8 = (const short8*)Vpk;

  // prologue: stage K tile 0 into K0lds (source-swizzled), full drain once
  {
    #pragma unroll
    for (int i2 = 0; i2 < 8; i2++) {
      int ch = w + 8 * i2;
      int a = ch >> 4, rr = ((ch & 15) << 2) + g;
      int u = c ^ (rr & 7);
      gload_lds16(FK + (((size_t)((a * 2 + b) * 4096) + rr) * 128 + u * 8),
                  K0lds + (size_t)ch * 512);
    }
    asm volatile("s_waitcnt vmcnt(0)" ::: "memory");
    __builtin_amdgcn_s_barrier();
    __builtin_amdgcn_sched_barrier(0);
  }

  auto STEP = [&](const short* kb, short* dmadst, int mt) {
    // issue next K tile DMA (has the full iteration to complete)
    if (mt + 1 < 64) {
      int m0 = (mt + 1) * 64;
      #pragma unroll
      for (int i2 = 0; i2 < 8; i2++) {
        int ch = w + 8 * i2;
        int a = ch >> 4, rr = ((ch & 15) << 2) + g;
        int u = c ^ (rr & 7);
        gload_lds16(FK + (((size_t)((a * 2 + b) * 4096) + m0 + rr) * 128 + u * 8),
                    dmadst + (size_t)ch * 512);
      }
    }
    __builtin_amdgcn_s_setprio(1);
    // PV(mt-1): rescale + accumulate
    if (mt > 0) {
      f32x4 ev = *(const f32x4*)&escs[qg][4 * g];
      #pragma unroll
      for (int r = 0; r < 4; r++) {
        #pragma unroll
        for (int nt = 0; nt < 4; nt++) O[nt][r] *= ev[r];
        Oe[r] *= ev[r];
      }
      #pragma unroll
      for (int ks = 0; ks < 2; ks++) {
        short8 Pa = *(const short8*)&Pfrag[(qg * 16 + c) * 72 + 32 * ks + 8 * g];
        #pragma unroll
        for (int nt = 0; nt < 4; nt++)
          O[nt] = MFMA16(Pa, Vreg[ks][nt], O[nt]);
        Oe = MFMA16(Pa, ones, Oe);
      }
    }
    // QK^T(mt), swapped, split bf16 hh+hl+lh; swizzled LDS reads
    const short8* kb8 = (const short8*)kb;
    f32x4 sr = (f32x4){0, 0, 0, 0}, si = (f32x4){0, 0, 0, 0};
    #pragma unroll
    for (int s = 0; s < 4; s++) {
      int base0 = (ms * 16 + c) * 16 + ((s * 4 + g) ^ (c & 7));
      short8 Arh = kb8[base0];
      short8 Arl = kb8[base0 + 1024];
      short8 Aih = kb8[base0 + 2048];
      short8 Ail = kb8[base0 + 3072];
      short8 nqh = neg8(Qf[2][s]);
      short8 nql = neg8(Qf[3][s]);
      sr = MFMA16(Arh, Qf[0][s], sr);
      si = MFMA16(Arh, Qf[2][s], si);
      sr = MFMA16(Arh, Qf[1][s], sr);
      si = MFMA16(Arh, Qf[3][s], si);
      sr = MFMA16(Arl, Qf[0][s], sr);
      si = MFMA16(Arl, Qf[2][s], si);
      sr = MFMA16(Aih, nqh, sr);
      si = MFMA16(Aih, Qf[0][s], si);
      sr = MFMA16(Aih, nql, sr);
      si = MFMA16(Aih, Qf[1][s], si);
      sr = MFMA16(Ail, nqh, sr);
      si = MFMA16(Ail, Qf[0][s], si);
    }
    __builtin_amdgcn_s_setprio(0);
    // scores + slice-max
    f32x4 s0;
    #pragma unroll
    for (int r = 0; r < 4; r++)
      s0[r] = sqrtf(sr[r] * sr[r] + si[r] * si[r] + 1e-8f);
    float mloc = fmaxf(fmaxf(s0[0], s0[1]), fmaxf(s0[2], s0[3]));
    mloc = fmaxf(mloc, __shfl_xor(mloc, 16));
    mloc = fmaxf(mloc, __shfl_xor(mloc, 32));
    if (l < 16) rmax[qg][l][ms] = mloc;
    // SYNC B: LDS-only visibility (NO vmcnt drain -> DMA stays in flight)
    asm volatile("s_waitcnt lgkmcnt(0)" ::: "memory");
    __builtin_amdgcn_s_barrier();
    __builtin_amdgcn_sched_barrier(0);
    {
      f32x4 rm4 = *(const f32x4*)&rmax[qg][c][0];
      float nmq = fmaxf(fmaxf(rm4[0], rm4[1]), fmaxf(rm4[2], rm4[3]));
      nmq = fmaxf(Mq, nmq);
      float escq = __expf(Mq - nmq);
      Mq = nmq;
      if (ms == 0 && l < 16) escs[qg][l] = escq;
      // V(mt) prefetch (8 vm loads; stay in flight across iter-end barrier)
      #pragma unroll
      for (int ks = 0; ks < 2; ks++)
        #pragma unroll
        for (int nt = 0; nt < 4; nt++)
          Vreg[ks][nt] = Vp8[((size_t)((b * 128 + mt * 2 + ks) * 16 + ms * 4 + nt)) * 64 + l];
      f32x4 p;
      #pragma unroll
      for (int r = 0; r < 4; r++) p[r] = __expf(s0[r] - nmq);
      unsigned int w01 = (unsigned int)f2bf(p[0]) | ((unsigned int)f2bf(p[1]) << 16);
      unsigned int w23 = (unsigned int)f2bf(p[2]) | ((unsigned int)f2bf(p[3]) << 16);
      unsigned int* pw = (unsigned int*)&Pfrag[(qg * 16 + c) * 72 + 16 * ms + 4 * g];
      pw[0] = w01; pw[1] = w23;
    }
    // SYNC A': counted vmcnt(8) -> drains the 8 K-DMA ops, leaves 8 V loads
    asm volatile("s_waitcnt vmcnt(8) lgkmcnt(0)" ::: "memory");
    __builtin_amdgcn_s_barrier();
    __builtin_amdgcn_sched_barrier(0);
  };

  for (int mt = 0; mt < 64; mt += 2) {
    STEP(K0lds, K1lds, mt);
    STEP(K1lds, K0lds, mt + 1);
  }
  // tail PV(63)
  {
    f32x4 ev = *(const f32x4*)&escs[qg][4 * g];
    #pragma unroll
    for (int r = 0; r < 4; r++) {
      #pragma unroll
      for (int nt = 0; nt < 4; nt++) O[nt][r] *= ev[r];
      Oe[r] *= ev[r];
    }
    #pragma unroll
    for (int ks = 0; ks < 2; ks++) {
      short8 Pa = *(const short8*)&Pfrag[(qg * 16 + c) * 72 + 32 * ks + 8 * g];
      #pragma unroll
      for (int nt = 0; nt < 4; nt++)
        O[nt] = MFMA16(Pa, Vreg[ks][nt], O[nt]);
      Oe = MFMA16(Pa, ones, Oe);
    }
  }
  // normalize + write out
  const size_t base = (size_t)b * 4096 * 128;
  f32x4 inv;
  #pragma unroll
  for (int r = 0; r < 4; r++) inv[r] = 1.0f / Oe[r];
  #pragma unroll
  for (int nt = 0; nt < 4; nt++) {
    int cc = ms * 64 + nt * 16 + c;
    #pragma unroll
    for (int r = 0; r < 4; r++) {
      int row = qt * 32 + qg * 16 + 4 * g + r;
      float v = O[nt][r] * inv[r];
      if (cc < 128) Or_[base + (size_t)row * 128 + cc] = v;
      else          Oi_[base + (size_t)row * 128 + cc - 128] = v;
    }
  }
}

// ---------------------------------------------------------------------------
// Kernel 4: inverse DFT2 (real part), output [b][c][h][w]
// ---------------------------------------------------------------------------
__global__ __launch_bounds__(256) void idft2_kernel(
    const float* __restrict__ Or_, const float* __restrict__ Oi_,
    float* __restrict__ out)
{
  __shared__ float Ar[4096], Ai[4096], Tr[4096], Ti[4096];
  __shared__ float twc[64], tws[64];
  int plane = blockIdx.x; int b = plane >> 7, c = plane & 127;
  int t = threadIdx.x;
  if (t < 64) {
    float ang = PI2 * (float)t / 64.0f;
    twc[t] = cosf(ang); tws[t] = sinf(ang);
  }
  size_t ibase = (size_t)b * 4096 * 128 + c;
  for (int i = t; i < 4096; i += 256) {
    Ar[i] = Or_[ibase + (size_t)i * 128];
    Ai[i] = Oi_[ibase + (size_t)i * 128];
  }
  __syncthreads();
  for (int j = 0; j < 16; j++) {
    int o = t + 256 * j; int hp = o >> 6, w = o & 63;
    float tr = 0.f, ti = 0.f;
    for (int wp = 0; wp < 64; wp++) {
      int k = (wp * w) & 63;
      float cr = twc[k], ci = tws[k];
      float ar = Ar[hp * 64 + wp], ai = Ai[hp * 64 + wp];
      tr += ar * cr - ai * ci;
      ti += ai * cr + ar * ci;
    }
    Tr[hp * 64 + w] = tr; Ti[hp * 64 + w] = ti;
  }
  __syncthreads();
  size_t obase = ((size_t)plane) << 12;
  for (int j = 0; j < 16; j++) {
    int o = t + 256 * j; int h = o >> 6, w = o & 63;
    float acc = 0.f;
    for (int hp = 0; hp < 64; hp++) {
      int k = (hp * h) & 63;
      acc += Tr[hp * 64 + w] * twc[k] - Ti[hp * 64 + w] * tws[k];
    }
    out[obase + o] = acc * (1.0f / 4096.0f);
  }
}

extern "C" void kernel_launch(void* const* d_in, const int* in_sizes, int n_in,
                              void* d_out, int out_size, void* d_ws, size_t ws_size,
                              hipStream_t stream) {
  const float* x   = (const float*)d_in[0];
  const float* y   = (const float*)d_in[1];
  const float* Wqr = (const float*)d_in[2];  const float* bqr = (const float*)d_in[3];
  const float* Wqi = (const float*)d_in[4];  const float* bqi = (const float*)d_in[5];
  const float* Wkr = (const float*)d_in[6];  const float* bkr = (const float*)d_in[7];
  const float* Wki = (const float*)d_in[8];  const float* bki = (const float*)d_in[9];
  const float* Wvr = (const float*)d_in[10]; const float* bvr = (const float*)d_in[11];
  const float* Wvi = (const float*)d_in[12]; const float* bvi = (const float*)d_in[13];
  char* wsb = (char*)d_ws;
  if (ws_size < ((size_t)40 << 20)) return;  // need 40 MiB
  unsigned short* FQ  = (unsigned short*)(wsb);                      // [0,8M)
  unsigned short* FK  = (unsigned short*)(wsb + ((size_t)8  << 20)); // [8,16M)
  unsigned short* FV  = (unsigned short*)(wsb + ((size_t)16 << 20)); // [16,20M)
  float* xr = (float*)(wsb + ((size_t)20 << 20));
  float* xi = (float*)(wsb + ((size_t)24 << 20));
  float* yr = (float*)(wsb + ((size_t)28 << 20));
  float* yi = (float*)(wsb + ((size_t)32 << 20));
  unsigned short* Vpk = (unsigned short*)(wsb + ((size_t)36 << 20)); // [36,40M)
  float* Or_ = (float*)(wsb + ((size_t)20 << 20));  // overlay dead xr
  float* Oi_ = (float*)(wsb + ((size_t)24 << 20));  // overlay dead xi
  float* out = (float*)d_out;

  hipLaunchKernelGGL(dft2_fwd_kernel, dim3(512), dim3(256), 0, stream,
                     x, y, xr, xi, yr, yi);
  hipLaunchKernelGGL(proj_kernel, dim3(64, 3, 2), dim3(256), 0, stream,
                     xr, xi, yr, yi,
                     Wqr, bqr, Wqi, bqi, Wkr, bkr, Wki, bki, Wvr, bvr, Wvi, bvi,
                     FQ, FK, FV);
  hipLaunchKernelGGL(vpack_kernel, dim3(256), dim3(256), 0, stream, FV, Vpk);
  hipLaunchKernelGGL(attn_mfma_kernel, dim3(256), dim3(512), 0, stream,
                     FQ, FK, (const short*)Vpk, Or_, Oi_);
  hipLaunchKernelGGL(idft2_kernel, dim3(256), dim3(256), 0, stream,
                     Or_, Oi_, out);
}